// Round 4
// baseline (1253.737 us; speedup 1.0000x reference)
//
#include <hip/hip_runtime.h>

typedef unsigned short ushort_t;

#define HWsz 16384
#define NHWsz 65536

__device__ __forceinline__ float b2f(ushort_t u){ return __uint_as_float(((unsigned)u)<<16); }
__device__ __forceinline__ ushort_t f2b(float f){
  unsigned x = __float_as_uint(f);
  x += 0x7fffu + ((x>>16)&1u);
  return (ushort_t)(x>>16);
}
__device__ __forceinline__ float gelu_exact(float x){
  return 0.5f*x*(1.0f+erff(x*0.70710678118654752f));
}

// ---------------- kA: LN1, NCHW fp32 -> NHWC bf16 ----------------
__global__ __launch_bounds__(256) void kA_ln1(const float* __restrict__ x,
    const float* __restrict__ w, const float* __restrict__ b,
    ushort_t* __restrict__ xcl){
  __shared__ float tile[128*66];
  __shared__ float psum[256], psq[256];
  __shared__ float ms[64], rs[64];
  int t = threadIdx.x;
  int pos0 = blockIdx.x * 64;
  int n = pos0 >> 14, hw0 = pos0 & 16383;
  const float* xb = x + (size_t)n*128*HWsz + hw0;
  for (int i=0;i<32;i++){
    int e = i*256+t;
    int c = e>>6, p = e&63;     // 64 consecutive lanes read 64 consecutive positions of one channel
    tile[c*66+p] = xb[(size_t)c*HWsz + p];
  }
  __syncthreads();
  {
    int part = t>>6, p = t&63;  // 4 partials per position
    float s=0.f, q=0.f;
    for (int c=part*32; c<part*32+32; c++){ float v = tile[c*66+p]; s+=v; q+=v*v; }
    psum[part*64+p]=s; psq[part*64+p]=q;
  }
  __syncthreads();
  if (t<64){
    float s=psum[t]+psum[64+t]+psum[128+t]+psum[192+t];
    float q=psq[t]+psq[64+t]+psq[128+t]+psq[192+t];
    float m = s*(1.0f/128.0f);
    float v = q*(1.0f/128.0f)-m*m;
    ms[t]=m; rs[t]=rsqrtf(v+1e-6f);
  }
  __syncthreads();
  for (int i=0;i<32;i++){
    int e = i*256+t;
    int p = e>>7, c = e&127;
    float v = (tile[c*66+p]-ms[p])*rs[p]*w[c]+b[c];
    xcl[(size_t)(pos0+p)*128 + c] = f2b(v);
  }
}

// ---------------- kB: depthwise 3x3 + bias + LN + GELU ----------------
__global__ __launch_bounds__(128) void kB_dw(const ushort_t* __restrict__ xcl,
    const float* __restrict__ dww, const float* __restrict__ dwb,
    const float* __restrict__ lnw, const float* __restrict__ lnb,
    ushort_t* __restrict__ x1){
  __shared__ float red[128];
  int t = threadIdx.x;
  int pos = blockIdx.x;
  int n = pos>>14, hw = pos & 16383, h = hw>>7, w = hw&127;
  float acc = dwb[t];
  #pragma unroll
  for (int kh=0; kh<3; kh++){
    int hy = h + kh - 1;
    if ((unsigned)hy < 128u){
      #pragma unroll
      for (int kw=0; kw<3; kw++){
        int wx = w + kw - 1;
        if ((unsigned)wx < 128u){
          acc += b2f(xcl[((size_t)(n*16384 + hy*128 + wx))*128 + t]) * dww[t*9+kh*3+kw];
        }
      }
    }
  }
  red[t] = acc;
  __syncthreads();
  for (int s=64; s>0; s>>=1){ if (t<s) red[t]+=red[t+s]; __syncthreads(); }
  float m = red[0]*(1.0f/128.0f);
  __syncthreads();
  red[t] = acc*acc;
  __syncthreads();
  for (int s=64; s>0; s>>=1){ if (t<s) red[t]+=red[t+s]; __syncthreads(); }
  float var = red[0]*(1.0f/128.0f) - m*m;
  float r = rsqrtf(var+1e-6f);
  float v = (acc-m)*r*lnw[t]+lnb[t];
  x1[(size_t)pos*128 + t] = f2b(gelu_exact(v));
}

// ---------------- kCD: fused offset/mask linears + softmax + deformable sampling ----
// one position per 128-thread block; no offset/mask global buffers.
__global__ __launch_bounds__(128) void kCD_dcn(const ushort_t* __restrict__ x1,
    const float* __restrict__ offw, const float* __restrict__ offb,
    const float* __restrict__ mw, const float* __restrict__ mb,
    ushort_t* __restrict__ dcnout){
  __shared__ __align__(16) float xL[128];
  __shared__ float offL[72];
  __shared__ float mraw[36];
  __shared__ float mskL[36];
  int t = threadIdx.x;
  int pos = blockIdx.x;
  int n = pos>>14, hw = pos&16383, h = hw>>7, w = hw&127;
  xL[t] = b2f(x1[(size_t)pos*128 + t]);
  __syncthreads();
  if (t < 108){
    const float* wrow = (t<72) ? (offw + t*128) : (mw + (t-72)*128);
    float acc = 0.f;
    for (int k=0;k<128;k+=4){
      const float4 wv = *(const float4*)(wrow+k);
      const float4 xv = *(const float4*)(xL + k);
      acc += wv.x*xv.x + wv.y*xv.y + wv.z*xv.z + wv.w*xv.w;
    }
    if (t<72) offL[t] = acc + offb[t];
    else      mraw[t-72] = acc + mb[t-72];
  }
  __syncthreads();
  if (t < 4){
    int g = t;
    float mx = -1e30f;
    for (int q=0;q<9;q++) mx = fmaxf(mx, mraw[g*9+q]);
    float e[9]; float ssum=0.f;
    for (int q=0;q<9;q++){ e[q]=expf(mraw[g*9+q]-mx); ssum+=e[q]; }
    float inv = 1.0f/ssum;
    for (int q=0;q<9;q++) mskL[g*9+q] = e[q]*inv;
  }
  __syncthreads();
  int g = t>>5;
  const ushort_t* xbase = x1 + (size_t)n*16384*128 + t;
  float acc = 0.f;
  #pragma unroll
  for (int p=0;p<9;p++){
    int i = p/3, j = p%3;  // dx = ks[i], dy = ks[j] (torch meshgrid 'ij')
    float ox = offL[2*(g*9+p)];
    float oy = offL[2*(g*9+p)+1];
    float px = (float)(w + i - 1) + ox;   // unpadded coords; pad ring == zeros
    float py = (float)(h + j - 1) + oy;
    float fx0 = floorf(px), fy0 = floorf(py);
    int ix0 = (int)fx0, iy0 = (int)fy0;
    float fx = px - fx0, fy = py - fy0;
    float mval = mskL[g*9+p];
    float w00=(1.f-fx)*(1.f-fy), w10=fx*(1.f-fy), w01=(1.f-fx)*fy, w11=fx*fy;
    float sv = 0.f;
    if ((unsigned)ix0<128u     && (unsigned)iy0<128u    ) sv += w00 * b2f(xbase[(size_t)(iy0*128+ix0)*128]);
    if ((unsigned)(ix0+1)<128u && (unsigned)iy0<128u    ) sv += w10 * b2f(xbase[(size_t)(iy0*128+ix0+1)*128]);
    if ((unsigned)ix0<128u     && (unsigned)(iy0+1)<128u) sv += w01 * b2f(xbase[(size_t)((iy0+1)*128+ix0)*128]);
    if ((unsigned)(ix0+1)<128u && (unsigned)(iy0+1)<128u) sv += w11 * b2f(xbase[(size_t)((iy0+1)*128+ix0+1)*128]);
    acc += mval * sv;
  }
  dcnout[(size_t)pos*128 + t] = f2b(acc);
}

// ---------------- kE: outproj + residual -> x2 (bf16); x is NCHW fp32 ----------------
__global__ __launch_bounds__(256) void kE_outproj(const ushort_t* __restrict__ dcnout,
    const float* __restrict__ pw, const float* __restrict__ pb,
    const float* __restrict__ x, ushort_t* __restrict__ x2){
  __shared__ __align__(16) float dt[16*128];
  __shared__ float xres[128*17];
  int t = threadIdx.x;
  int pos0 = blockIdx.x*16;
  int n = pos0>>14, hw0 = pos0&16383;
  for (int i=0;i<8;i++){
    int e = i*256+t;
    dt[e] = b2f(dcnout[(size_t)pos0*128 + e]);
  }
  const float* xb = x + (size_t)n*128*HWsz + hw0;
  for (int i=0;i<8;i++){
    int e = i*256+t;
    int c = e>>4, p = e&15;
    xres[c*17+p] = xb[(size_t)c*HWsz + p];
  }
  __syncthreads();
  int c = t&127, ph = t>>7;
  float acc[8];
  #pragma unroll
  for (int j=0;j<8;j++) acc[j]=0.f;
  const float* wrow = pw + c*128;
  for (int k=0;k<128;k+=4){
    const float4 wv = *(const float4*)(wrow+k);
    #pragma unroll
    for (int j=0;j<8;j++){
      const float4 xv = *(const float4*)(dt + (ph*8+j)*128 + k);
      acc[j] += wv.x*xv.x+wv.y*xv.y+wv.z*xv.z+wv.w*xv.w;
    }
  }
  float bias = pb[c];
  for (int j=0;j<8;j++){
    int p = ph*8+j;
    x2[(size_t)(pos0+p)*128+c] = f2b(acc[j] + bias + xres[c*17+p]);
  }
}

// ---------------- kFG: fused LN2 + MLP 128->512(gelu)->128 ----------------
__global__ __launch_bounds__(256) void kFG_mlp(const ushort_t* __restrict__ x2,
    const float* __restrict__ n2w, const float* __restrict__ n2b,
    const float* __restrict__ w1, const float* __restrict__ b1,
    const float* __restrict__ w2, const float* __restrict__ b2,
    ushort_t* __restrict__ mlpout){
  __shared__ __align__(16) float yv[16*128];
  __shared__ __align__(16) float hid[16*512];
  __shared__ float part[16*34];
  __shared__ float ms[16], rs[16];
  int t = threadIdx.x;
  int pos0 = blockIdx.x*16;
  for (int i=0;i<8;i++){
    int e = i*256+t;
    yv[e] = b2f(x2[(size_t)pos0*128 + e]);
  }
  __syncthreads();
  {
    int tg = t>>4, l = t&15;     // 16 lanes per position, 8 channels each
    float s=0.f, q=0.f;
    for (int j=0;j<8;j++){ float v = yv[tg*128 + l*8 + j]; s+=v; q+=v*v; }
    part[tg*34 + l] = s; part[tg*34 + 17 + l] = q;
  }
  __syncthreads();
  if (t < 16){
    float s=0.f, q=0.f;
    for (int l=0;l<16;l++){ s += part[t*34+l]; q += part[t*34+17+l]; }
    float m = s*(1.0f/128.0f);
    float var = q*(1.0f/128.0f) - m*m;
    ms[t]=m; rs[t]=rsqrtf(var+1e-6f);
  }
  __syncthreads();
  for (int i=0;i<8;i++){
    int e = i*256+t;
    int p = e>>7, c = e&127;
    yv[e] = (yv[e]-ms[p])*rs[p]*n2w[c] + n2b[c];
  }
  __syncthreads();
  for (int rep=0; rep<2; rep++){
    int o = rep*256 + t;
    float acc[16];
    #pragma unroll
    for (int p=0;p<16;p++) acc[p]=0.f;
    const float* wrow = w1 + (size_t)o*128;
    for (int k=0;k<128;k+=4){
      const float4 wv = *(const float4*)(wrow+k);
      #pragma unroll
      for (int p=0;p<16;p++){
        const float4 xv = *(const float4*)(yv + p*128 + k);
        acc[p] += wv.x*xv.x+wv.y*xv.y+wv.z*xv.z+wv.w*xv.w;
      }
    }
    float bias = b1[o];
    #pragma unroll
    for (int p=0;p<16;p++) hid[p*512+o] = gelu_exact(acc[p]+bias);
    __syncthreads();
  }
  int c = t&127, ph = t>>7;
  float acc2[8];
  #pragma unroll
  for (int j=0;j<8;j++) acc2[j]=0.f;
  const float* wrow2 = w2 + (size_t)c*512;
  for (int k=0;k<512;k+=4){
    const float4 wv = *(const float4*)(wrow2+k);
    #pragma unroll
    for (int j=0;j<8;j++){
      const float4 hv = *(const float4*)(hid + (ph*8+j)*512 + k);
      acc2[j] += wv.x*hv.x+wv.y*hv.y+wv.z*hv.z+wv.w*hv.w;
    }
  }
  float bias2 = b2[c];
  for (int j=0;j<8;j++){
    int p = ph*8+j;
    mlpout[(size_t)(pos0+p)*128+c] = f2b(acc2[j]+bias2);
  }
}

// ---------------- kH: final residual add + NHWC->NCHW fp32 out ----------------
__global__ __launch_bounds__(256) void kH_final(const ushort_t* __restrict__ x2,
    const ushort_t* __restrict__ mlpout, float* __restrict__ out){
  __shared__ float tile[64*130];
  int t = threadIdx.x;
  int pos0 = blockIdx.x*64;
  int n = pos0>>14, hw0 = pos0&16383;
  for (int i=0;i<32;i++){
    int e = i*256+t;
    int p = e>>7, c = e&127;
    tile[p*130+c] = b2f(x2[(size_t)pos0*128+e]) + b2f(mlpout[(size_t)pos0*128+e]);
  }
  __syncthreads();
  float* ob = out + (size_t)n*128*HWsz + hw0;
  for (int i=0;i<32;i++){
    int e = i*256+t;
    int c = e>>6, p = e&63;
    ob[(size_t)c*HWsz + p] = tile[p*130+c];
  }
}

extern "C" void kernel_launch(void* const* d_in, const int* in_sizes, int n_in,
                              void* d_out, int out_size, void* d_ws, size_t ws_size,
                              hipStream_t stream){
  const float* x     = (const float*)d_in[0];
  const float* n1w   = (const float*)d_in[1];
  const float* n1b   = (const float*)d_in[2];
  const float* dww   = (const float*)d_in[3];
  const float* dwb   = (const float*)d_in[4];
  const float* dwlnw = (const float*)d_in[5];
  const float* dwlnb = (const float*)d_in[6];
  const float* offw  = (const float*)d_in[7];
  const float* offb  = (const float*)d_in[8];
  const float* maskw = (const float*)d_in[9];
  const float* maskb = (const float*)d_in[10];
  const float* pw    = (const float*)d_in[11];
  const float* pb    = (const float*)d_in[12];
  const float* n2w   = (const float*)d_in[13];
  const float* n2b   = (const float*)d_in[14];
  const float* w1    = (const float*)d_in[15];
  const float* b1    = (const float*)d_in[16];
  const float* w2    = (const float*)d_in[17];
  const float* b2    = (const float*)d_in[18];

  // ws layout: 32 MB total, two 16 MB bf16 regions with liveness aliasing:
  //  R0 = ws[ 0,16MB): xcl (kA->kB) -> dcnout (kCD->kE) -> mlpout (kFG->kH)
  //  R1 = ws[16,32MB): x1  (kB->kCD) -> x2 (kE->kFG,kH)
  char* wsb = (char*)d_ws;
  ushort_t* R0 = (ushort_t*)(wsb);
  ushort_t* R1 = (ushort_t*)(wsb + (16u<<20));
  float* out = (float*)d_out;

  hipLaunchKernelGGL(kA_ln1,  dim3(1024),  dim3(256), 0, stream, x, n1w, n1b, R0);
  hipLaunchKernelGGL(kB_dw,   dim3(65536), dim3(128), 0, stream, R0, dww, dwb, dwlnw, dwlnb, R1);
  hipLaunchKernelGGL(kCD_dcn, dim3(65536), dim3(128), 0, stream, R1, offw, offb, maskw, maskb, R0);
  hipLaunchKernelGGL(kE_outproj, dim3(4096), dim3(256), 0, stream, R0, pw, pb, x, R1);
  hipLaunchKernelGGL(kFG_mlp, dim3(4096),  dim3(256), 0, stream, R1, n2w, n2b, w1, b1, w2, b2, R0);
  hipLaunchKernelGGL(kH_final,dim3(1024),  dim3(256), 0, stream, R1, R0, out);
}

// Round 5
// 881.163 us; speedup vs baseline: 1.4228x; 1.4228x over previous
//
#include <hip/hip_runtime.h>

typedef unsigned short ushort_t;
typedef short short8 __attribute__((ext_vector_type(8)));
typedef float f32x4 __attribute__((ext_vector_type(4)));

#define HWsz 16384
#define NHWsz 65536

__device__ __forceinline__ float b2f(ushort_t u){ return __uint_as_float(((unsigned)u)<<16); }
__device__ __forceinline__ ushort_t f2b(float f){
  unsigned x = __float_as_uint(f);
  x += 0x7fffu + ((x>>16)&1u);
  return (ushort_t)(x>>16);
}
__device__ __forceinline__ float gelu_exact(float x){
  return 0.5f*x*(1.0f+erff(x*0.70710678118654752f));
}

// ---------------- kW: convert MLP weights fp32 -> bf16 (once per launch) ----------------
__global__ __launch_bounds__(256) void kW_cvt(const float* __restrict__ w1, const float* __restrict__ w2,
    ushort_t* __restrict__ w1b, ushort_t* __restrict__ w2b){
  int i = blockIdx.x*256 + threadIdx.x;   // 65536 each
  w1b[i] = f2b(w1[i]);
  w2b[i] = f2b(w2[i]);
}

// ---------------- kA: LN1, NCHW fp32 -> NHWC bf16 ----------------
__global__ __launch_bounds__(256) void kA_ln1(const float* __restrict__ x,
    const float* __restrict__ w, const float* __restrict__ b,
    ushort_t* __restrict__ xcl){
  __shared__ float tile[128*66];
  __shared__ float psum[256], psq[256];
  __shared__ float ms[64], rs[64];
  int t = threadIdx.x;
  int pos0 = blockIdx.x * 64;
  int n = pos0 >> 14, hw0 = pos0 & 16383;
  const float* xb = x + (size_t)n*128*HWsz + hw0;
  for (int i=0;i<32;i++){
    int e = i*256+t;
    int c = e>>6, p = e&63;
    tile[c*66+p] = xb[(size_t)c*HWsz + p];
  }
  __syncthreads();
  {
    int part = t>>6, p = t&63;
    float s=0.f, q=0.f;
    for (int c=part*32; c<part*32+32; c++){ float v = tile[c*66+p]; s+=v; q+=v*v; }
    psum[part*64+p]=s; psq[part*64+p]=q;
  }
  __syncthreads();
  if (t<64){
    float s=psum[t]+psum[64+t]+psum[128+t]+psum[192+t];
    float q=psq[t]+psq[64+t]+psq[128+t]+psq[192+t];
    float m = s*(1.0f/128.0f);
    float v = q*(1.0f/128.0f)-m*m;
    ms[t]=m; rs[t]=rsqrtf(v+1e-6f);
  }
  __syncthreads();
  for (int i=0;i<32;i++){
    int e = i*256+t;
    int p = e>>7, c = e&127;
    float v = (tile[c*66+p]-ms[p])*rs[p]*w[c]+b[c];
    xcl[(size_t)(pos0+p)*128 + c] = f2b(v);
  }
}

// ---------------- kB: depthwise 3x3 + bias + LN + GELU ----------------
__global__ __launch_bounds__(128) void kB_dw(const ushort_t* __restrict__ xcl,
    const float* __restrict__ dww, const float* __restrict__ dwb,
    const float* __restrict__ lnw, const float* __restrict__ lnb,
    ushort_t* __restrict__ x1){
  __shared__ float red[128];
  int t = threadIdx.x;
  int pos = blockIdx.x;
  int n = pos>>14, hw = pos & 16383, h = hw>>7, w = hw&127;
  float acc = dwb[t];
  #pragma unroll
  for (int kh=0; kh<3; kh++){
    int hy = h + kh - 1;
    if ((unsigned)hy < 128u){
      #pragma unroll
      for (int kw=0; kw<3; kw++){
        int wx = w + kw - 1;
        if ((unsigned)wx < 128u){
          acc += b2f(xcl[((size_t)(n*16384 + hy*128 + wx))*128 + t]) * dww[t*9+kh*3+kw];
        }
      }
    }
  }
  red[t] = acc;
  __syncthreads();
  for (int s=64; s>0; s>>=1){ if (t<s) red[t]+=red[t+s]; __syncthreads(); }
  float m = red[0]*(1.0f/128.0f);
  __syncthreads();
  red[t] = acc*acc;
  __syncthreads();
  for (int s=64; s>0; s>>=1){ if (t<s) red[t]+=red[t+s]; __syncthreads(); }
  float var = red[0]*(1.0f/128.0f) - m*m;
  float r = rsqrtf(var+1e-6f);
  float v = (acc-m)*r*lnw[t]+lnb[t];
  x1[(size_t)pos*128 + t] = f2b(gelu_exact(v));
}

// ---------------- kCD: fused offset/mask linears + softmax + deformable sampling ----
__global__ __launch_bounds__(128) void kCD_dcn(const ushort_t* __restrict__ x1,
    const float* __restrict__ offw, const float* __restrict__ offb,
    const float* __restrict__ mw, const float* __restrict__ mb,
    ushort_t* __restrict__ dcnout){
  __shared__ __align__(16) float xL[128];
  __shared__ float offL[72];
  __shared__ float mraw[36];
  __shared__ float mskL[36];
  int t = threadIdx.x;
  int pos = blockIdx.x;
  int n = pos>>14, hw = pos&16383, h = hw>>7, w = hw&127;
  xL[t] = b2f(x1[(size_t)pos*128 + t]);
  __syncthreads();
  if (t < 108){
    const float* wrow = (t<72) ? (offw + t*128) : (mw + (t-72)*128);
    float acc = 0.f;
    for (int k=0;k<128;k+=4){
      const float4 wv = *(const float4*)(wrow+k);
      const float4 xv = *(const float4*)(xL + k);
      acc += wv.x*xv.x + wv.y*xv.y + wv.z*xv.z + wv.w*xv.w;
    }
    if (t<72) offL[t] = acc + offb[t];
    else      mraw[t-72] = acc + mb[t-72];
  }
  __syncthreads();
  if (t < 4){
    int g = t;
    float mx = -1e30f;
    for (int q=0;q<9;q++) mx = fmaxf(mx, mraw[g*9+q]);
    float e[9]; float ssum=0.f;
    for (int q=0;q<9;q++){ e[q]=expf(mraw[g*9+q]-mx); ssum+=e[q]; }
    float inv = 1.0f/ssum;
    for (int q=0;q<9;q++) mskL[g*9+q] = e[q]*inv;
  }
  __syncthreads();
  int g = t>>5;
  const ushort_t* xbase = x1 + (size_t)n*16384*128 + t;
  float acc = 0.f;
  #pragma unroll
  for (int p=0;p<9;p++){
    int i = p/3, j = p%3;  // dx = ks[i], dy = ks[j] (torch meshgrid 'ij')
    float ox = offL[2*(g*9+p)];
    float oy = offL[2*(g*9+p)+1];
    float px = (float)(w + i - 1) + ox;
    float py = (float)(h + j - 1) + oy;
    float fx0 = floorf(px), fy0 = floorf(py);
    int ix0 = (int)fx0, iy0 = (int)fy0;
    float fx = px - fx0, fy = py - fy0;
    float mval = mskL[g*9+p];
    float w00=(1.f-fx)*(1.f-fy), w10=fx*(1.f-fy), w01=(1.f-fx)*fy, w11=fx*fy;
    float sv = 0.f;
    if ((unsigned)ix0<128u     && (unsigned)iy0<128u    ) sv += w00 * b2f(xbase[(size_t)(iy0*128+ix0)*128]);
    if ((unsigned)(ix0+1)<128u && (unsigned)iy0<128u    ) sv += w10 * b2f(xbase[(size_t)(iy0*128+ix0+1)*128]);
    if ((unsigned)ix0<128u     && (unsigned)(iy0+1)<128u) sv += w01 * b2f(xbase[(size_t)((iy0+1)*128+ix0)*128]);
    if ((unsigned)(ix0+1)<128u && (unsigned)(iy0+1)<128u) sv += w11 * b2f(xbase[(size_t)((iy0+1)*128+ix0+1)*128]);
    acc += mval * sv;
  }
  dcnout[(size_t)pos*128 + t] = f2b(acc);
}

// ---------------- kE: outproj + residual -> x2 (bf16); x is NCHW fp32 ----------------
__global__ __launch_bounds__(256) void kE_outproj(const ushort_t* __restrict__ dcnout,
    const float* __restrict__ pw, const float* __restrict__ pb,
    const float* __restrict__ x, ushort_t* __restrict__ x2){
  __shared__ __align__(16) float dt[16*128];
  __shared__ float xres[128*17];
  int t = threadIdx.x;
  int pos0 = blockIdx.x*16;
  int n = pos0>>14, hw0 = pos0&16383;
  for (int i=0;i<8;i++){
    int e = i*256+t;
    dt[e] = b2f(dcnout[(size_t)pos0*128 + e]);
  }
  const float* xb = x + (size_t)n*128*HWsz + hw0;
  for (int i=0;i<8;i++){
    int e = i*256+t;
    int c = e>>4, p = e&15;
    xres[c*17+p] = xb[(size_t)c*HWsz + p];
  }
  __syncthreads();
  int c = t&127, ph = t>>7;
  float acc[8];
  #pragma unroll
  for (int j=0;j<8;j++) acc[j]=0.f;
  const float* wrow = pw + c*128;
  for (int k=0;k<128;k+=4){
    const float4 wv = *(const float4*)(wrow+k);
    #pragma unroll
    for (int j=0;j<8;j++){
      const float4 xv = *(const float4*)(dt + (ph*8+j)*128 + k);
      acc[j] += wv.x*xv.x+wv.y*xv.y+wv.z*xv.z+wv.w*xv.w;
    }
  }
  float bias = pb[c];
  for (int j=0;j<8;j++){
    int p = ph*8+j;
    x2[(size_t)(pos0+p)*128+c] = f2b(acc[j] + bias + xres[c*17+p]);
  }
}

// ---------------- kFG: fused LN2 + MFMA MLP 128->512(gelu)->128 ----------------
// 16 positions per 256-thread block (4 waves).
// MFMA A layout: A[m=lane&15][k=(lane>>4)*8+j]; C/D: col=lane&15, row=(lane>>4)*4+reg.
__global__ __launch_bounds__(256) void kFG_mfma(const ushort_t* __restrict__ x2,
    const float* __restrict__ n2w, const float* __restrict__ n2b,
    const ushort_t* __restrict__ w1b, const float* __restrict__ b1,
    const ushort_t* __restrict__ w2b, const float* __restrict__ b2,
    ushort_t* __restrict__ mlpout){
  __shared__ __align__(16) ushort_t yln[16*128];   // bf16 [m][k]
  __shared__ __align__(16) ushort_t hid[16*512];   // bf16 [m][k]
  __shared__ float part[16*34];
  __shared__ float ms[16], rs[16];
  int t = threadIdx.x;
  int pos0 = blockIdx.x*16;

  // --- LN2 (thread t: position t>>4, 8 channels) ---
  float vals[8];
  {
    int tg = t>>4, l = t&15;
    float s=0.f, q=0.f;
    for (int j=0;j<8;j++){
      float v = b2f(x2[(size_t)(pos0+tg)*128 + l*8 + j]);
      vals[j]=v; s+=v; q+=v*v;
    }
    part[tg*34 + l] = s; part[tg*34 + 17 + l] = q;
  }
  __syncthreads();
  if (t < 16){
    float s=0.f, q=0.f;
    for (int l=0;l<16;l++){ s += part[t*34+l]; q += part[t*34+17+l]; }
    float m = s*(1.0f/128.0f);
    float var = q*(1.0f/128.0f) - m*m;
    ms[t]=m; rs[t]=rsqrtf(var+1e-6f);
  }
  __syncthreads();
  {
    int tg = t>>4, l = t&15;
    float m = ms[tg], r = rs[tg];
    for (int j=0;j<8;j++){
      int c = l*8+j;
      yln[tg*128 + c] = f2b((vals[j]-m)*r*n2w[c] + n2b[c]);
    }
  }
  __syncthreads();

  int wave = t>>6, lane = t&63;
  int ma = lane&15, quad = lane>>4;

  // --- FC1: wave covers n in [wave*128, wave*128+128), K=128 ---
  short8 afrag[4];
  #pragma unroll
  for (int ks=0; ks<4; ks++)
    afrag[ks] = *(const short8*)(yln + ma*128 + ks*32 + quad*8);
  f32x4 acc[8];
  #pragma unroll
  for (int i=0;i<8;i++) acc[i] = (f32x4){0.f,0.f,0.f,0.f};
  int nbase = wave*128;
  #pragma unroll
  for (int tile=0; tile<8; tile++){
    const ushort_t* brow = w1b + (size_t)(nbase + tile*16 + ma)*128 + quad*8;
    #pragma unroll
    for (int ks=0; ks<4; ks++){
      short8 bfrag = *(const short8*)(brow + ks*32);
      acc[tile] = __builtin_amdgcn_mfma_f32_16x16x32_bf16(afrag[ks], bfrag, acc[tile], 0,0,0);
    }
  }
  #pragma unroll
  for (int tile=0; tile<8; tile++){
    int nn = nbase + tile*16 + ma;
    float bias = b1[nn];
    #pragma unroll
    for (int r=0;r<4;r++){
      int m = quad*4 + r;
      hid[m*512 + nn] = f2b(gelu_exact(acc[tile][r] + bias));
    }
  }
  __syncthreads();

  // --- FC2: wave covers c in [wave*32, wave*32+32), K=512 ---
  f32x4 acc2[2];
  acc2[0] = (f32x4){0.f,0.f,0.f,0.f};
  acc2[1] = (f32x4){0.f,0.f,0.f,0.f};
  for (int ks=0; ks<16; ks++){
    short8 af = *(const short8*)(hid + ma*512 + ks*32 + quad*8);
    #pragma unroll
    for (int tile=0; tile<2; tile++){
      int c0 = wave*32 + tile*16;
      short8 bf = *(const short8*)(w2b + (size_t)(c0 + ma)*512 + ks*32 + quad*8);
      acc2[tile] = __builtin_amdgcn_mfma_f32_16x16x32_bf16(af, bf, acc2[tile], 0,0,0);
    }
  }
  #pragma unroll
  for (int tile=0; tile<2; tile++){
    int c = wave*32 + tile*16 + ma;
    float bias = b2[c];
    #pragma unroll
    for (int r=0;r<4;r++){
      int m = quad*4 + r;
      mlpout[(size_t)(pos0+m)*128 + c] = f2b(acc2[tile][r] + bias);
    }
  }
}

// ---------------- kH: final residual add + NHWC->NCHW fp32 out ----------------
__global__ __launch_bounds__(256) void kH_final(const ushort_t* __restrict__ x2,
    const ushort_t* __restrict__ mlpout, float* __restrict__ out){
  __shared__ float tile[64*130];
  int t = threadIdx.x;
  int pos0 = blockIdx.x*64;
  int n = pos0>>14, hw0 = pos0&16383;
  for (int i=0;i<32;i++){
    int e = i*256+t;
    int p = e>>7, c = e&127;
    tile[p*130+c] = b2f(x2[(size_t)pos0*128+e]) + b2f(mlpout[(size_t)pos0*128+e]);
  }
  __syncthreads();
  float* ob = out + (size_t)n*128*HWsz + hw0;
  for (int i=0;i<32;i++){
    int e = i*256+t;
    int c = e>>6, p = e&63;
    ob[(size_t)c*HWsz + p] = tile[p*130+c];
  }
}

extern "C" void kernel_launch(void* const* d_in, const int* in_sizes, int n_in,
                              void* d_out, int out_size, void* d_ws, size_t ws_size,
                              hipStream_t stream){
  const float* x     = (const float*)d_in[0];
  const float* n1w   = (const float*)d_in[1];
  const float* n1b   = (const float*)d_in[2];
  const float* dww   = (const float*)d_in[3];
  const float* dwb   = (const float*)d_in[4];
  const float* dwlnw = (const float*)d_in[5];
  const float* dwlnb = (const float*)d_in[6];
  const float* offw  = (const float*)d_in[7];
  const float* offb  = (const float*)d_in[8];
  const float* maskw = (const float*)d_in[9];
  const float* maskb = (const float*)d_in[10];
  const float* pw    = (const float*)d_in[11];
  const float* pb    = (const float*)d_in[12];
  const float* n2w   = (const float*)d_in[13];
  const float* n2b   = (const float*)d_in[14];
  const float* w1    = (const float*)d_in[15];
  const float* b1    = (const float*)d_in[16];
  const float* w2    = (const float*)d_in[17];
  const float* b2    = (const float*)d_in[18];

  // ws layout:
  //  R0 = ws[ 0,16MB): xcl (kA->kB) -> dcnout (kCD->kE) -> mlpout (kFG->kH)
  //  R1 = ws[16,32MB): x1  (kB->kCD) -> x2 (kE->kFG,kH)
  //  +32MB: w1b (128KB bf16), w2b (128KB bf16)
  char* wsb = (char*)d_ws;
  ushort_t* R0  = (ushort_t*)(wsb);
  ushort_t* R1  = (ushort_t*)(wsb + (16u<<20));
  ushort_t* w1b = (ushort_t*)(wsb + (32u<<20));
  ushort_t* w2b = (ushort_t*)(wsb + (32u<<20) + (128u<<10));
  float* out = (float*)d_out;

  hipLaunchKernelGGL(kW_cvt,  dim3(256),   dim3(256), 0, stream, w1, w2, w1b, w2b);
  hipLaunchKernelGGL(kA_ln1,  dim3(1024),  dim3(256), 0, stream, x, n1w, n1b, R0);
  hipLaunchKernelGGL(kB_dw,   dim3(65536), dim3(128), 0, stream, R0, dww, dwb, dwlnw, dwlnb, R1);
  hipLaunchKernelGGL(kCD_dcn, dim3(65536), dim3(128), 0, stream, R1, offw, offb, maskw, maskb, R0);
  hipLaunchKernelGGL(kE_outproj, dim3(4096), dim3(256), 0, stream, R0, pw, pb, x, R1);
  hipLaunchKernelGGL(kFG_mfma, dim3(4096), dim3(256), 0, stream, R1, n2w, n2b, w1b, b1, w2b, b2, R0);
  hipLaunchKernelGGL(kH_final, dim3(1024), dim3(256), 0, stream, R1, R0, out);
}

// Round 6
// 452.899 us; speedup vs baseline: 2.7683x; 1.9456x over previous
//
#include <hip/hip_runtime.h>

typedef unsigned short ushort_t;
typedef short short8 __attribute__((ext_vector_type(8)));
typedef float f32x4 __attribute__((ext_vector_type(4)));
typedef ushort_t ushort8v __attribute__((ext_vector_type(8)));

#define HWsz 16384
#define NHWsz 65536

__device__ __forceinline__ float b2f(ushort_t u){ return __uint_as_float(((unsigned)u)<<16); }
__device__ __forceinline__ ushort_t f2b(float f){
  unsigned x = __float_as_uint(f);
  x += 0x7fffu + ((x>>16)&1u);
  return (ushort_t)(x>>16);
}
__device__ __forceinline__ float gelu_exact(float x){
  return 0.5f*x*(1.0f+erff(x*0.70710678118654752f));
}

// ---------------- kW: convert weights fp32 -> bf16 (once per launch) ----------------
// w1/w2 (65536 each) + combined offset/mask weights into 128x128 padded block.
__global__ __launch_bounds__(256) void kW_cvt(const float* __restrict__ w1, const float* __restrict__ w2,
    const float* __restrict__ offw, const float* __restrict__ maskw,
    ushort_t* __restrict__ w1b, ushort_t* __restrict__ w2b, ushort_t* __restrict__ owmb){
  int i = blockIdx.x*256 + threadIdx.x;   // 65536
  w1b[i] = f2b(w1[i]);
  w2b[i] = f2b(w2[i]);
  if (i < 16384){
    int row = i >> 7, k = i & 127;
    float v = 0.f;
    if (row < 72) v = offw[row*128 + k];
    else if (row < 108) v = maskw[(row-72)*128 + k];
    owmb[i] = f2b(v);
  }
}

// ---------------- kA: LN1, NCHW fp32 -> NHWC bf16 ----------------
__global__ __launch_bounds__(256) void kA_ln1(const float* __restrict__ x,
    const float* __restrict__ w, const float* __restrict__ b,
    ushort_t* __restrict__ xcl){
  __shared__ float tile[128*66];
  __shared__ float psum[256], psq[256];
  __shared__ float ms[64], rs[64];
  int t = threadIdx.x;
  int pos0 = blockIdx.x * 64;
  int n = pos0 >> 14, hw0 = pos0 & 16383;
  const float* xb = x + (size_t)n*128*HWsz + hw0;
  for (int i=0;i<32;i++){
    int e = i*256+t;
    int c = e>>6, p = e&63;
    tile[c*66+p] = xb[(size_t)c*HWsz + p];
  }
  __syncthreads();
  {
    int part = t>>6, p = t&63;
    float s=0.f, q=0.f;
    for (int c=part*32; c<part*32+32; c++){ float v = tile[c*66+p]; s+=v; q+=v*v; }
    psum[part*64+p]=s; psq[part*64+p]=q;
  }
  __syncthreads();
  if (t<64){
    float s=psum[t]+psum[64+t]+psum[128+t]+psum[192+t];
    float q=psq[t]+psq[64+t]+psq[128+t]+psq[192+t];
    float m = s*(1.0f/128.0f);
    float v = q*(1.0f/128.0f)-m*m;
    ms[t]=m; rs[t]=rsqrtf(v+1e-6f);
  }
  __syncthreads();
  for (int i=0;i<32;i++){
    int e = i*256+t;
    int p = e>>7, c = e&127;
    float v = (tile[c*66+p]-ms[p])*rs[p]*w[c]+b[c];
    xcl[(size_t)(pos0+p)*128 + c] = f2b(v);
  }
}

// ---------------- kB: depthwise 3x3 + bias + LN + GELU ----------------
__global__ __launch_bounds__(128) void kB_dw(const ushort_t* __restrict__ xcl,
    const float* __restrict__ dww, const float* __restrict__ dwb,
    const float* __restrict__ lnw, const float* __restrict__ lnb,
    ushort_t* __restrict__ x1){
  __shared__ float red[128];
  int t = threadIdx.x;
  int pos = blockIdx.x;
  int n = pos>>14, hw = pos & 16383, h = hw>>7, w = hw&127;
  float acc = dwb[t];
  #pragma unroll
  for (int kh=0; kh<3; kh++){
    int hy = h + kh - 1;
    if ((unsigned)hy < 128u){
      #pragma unroll
      for (int kw=0; kw<3; kw++){
        int wx = w + kw - 1;
        if ((unsigned)wx < 128u){
          acc += b2f(xcl[((size_t)(n*16384 + hy*128 + wx))*128 + t]) * dww[t*9+kh*3+kw];
        }
      }
    }
  }
  red[t] = acc;
  __syncthreads();
  for (int s=64; s>0; s>>=1){ if (t<s) red[t]+=red[t+s]; __syncthreads(); }
  float m = red[0]*(1.0f/128.0f);
  __syncthreads();
  red[t] = acc*acc;
  __syncthreads();
  for (int s=64; s>0; s>>=1){ if (t<s) red[t]+=red[t+s]; __syncthreads(); }
  float var = red[0]*(1.0f/128.0f) - m*m;
  float r = rsqrtf(var+1e-6f);
  float v = (acc-m)*r*lnw[t]+lnb[t];
  x1[(size_t)pos*128 + t] = f2b(gelu_exact(v));
}

// ---------------- kCD v2: MFMA offset/mask + softmax + descriptor + vectorized sampling ----
// 16 positions per 256-thread block. All 16 positions share the same (n,h); w = w0..w0+15.
#define RS 120
__global__ __launch_bounds__(256) void kCD_dcn(const ushort_t* __restrict__ x1,
    const ushort_t* __restrict__ owmb, const float* __restrict__ offb,
    const float* __restrict__ mb, ushort_t* __restrict__ dcnout){
  __shared__ __align__(16) ushort_t xLb[16*128];   // bf16 A-tile [pos][k]
  __shared__ float raw[16*RS];                     // [pos][row<112] linear out; rows 72..107 become softmaxed mask
  __shared__ __align__(16) float desc[576*8];      // [pos*36+g*9+p][{w00,w10,w01,w11, o00,o10,o01,o11}]
  int t = threadIdx.x;
  int pos0 = blockIdx.x*16;
  int n = pos0>>14, hw0 = pos0&16383, h = hw0>>7, w0 = hw0&127;
  const size_t imgbase = (size_t)n*16384*128;

  // phase 1: stage x1 tile (contiguous copy, 16B per thread)
  *(ushort8v*)(xLb + t*8) = *(const ushort8v*)(x1 + (size_t)pos0*128 + t*8);
  __syncthreads();

  // phase 2: MFMA linear — out[pos][row], rows 0..111 (padded weight block is 128 rows)
  {
    int wave = t>>6, lane = t&63;
    int ma = lane&15, quad = lane>>4;
    short8 afrag[4];
    #pragma unroll
    for (int ks=0; ks<4; ks++)
      afrag[ks] = *(const short8*)(xLb + ma*128 + ks*32 + quad*8);
    f32x4 acc[2];
    acc[0] = (f32x4){0.f,0.f,0.f,0.f};
    acc[1] = (f32x4){0.f,0.f,0.f,0.f};
    #pragma unroll
    for (int tile=0; tile<2; tile++){
      const ushort_t* brow = owmb + (size_t)(wave*32 + tile*16 + ma)*128 + quad*8;
      #pragma unroll
      for (int ks=0; ks<4; ks++){
        short8 bfrag = *(const short8*)(brow + ks*32);
        acc[tile] = __builtin_amdgcn_mfma_f32_16x16x32_bf16(afrag[ks], bfrag, acc[tile], 0,0,0);
      }
    }
    #pragma unroll
    for (int tile=0; tile<2; tile++){
      int row = wave*32 + tile*16 + ma;
      if (row < 112){
        float bias = (row < 72) ? offb[row] : ((row < 108) ? mb[row-72] : 0.f);
        #pragma unroll
        for (int r=0;r<4;r++){
          int m = quad*4 + r;   // position index
          raw[m*RS + row] = acc[tile][r] + bias;
        }
      }
    }
  }
  __syncthreads();

  // phase 3a: softmax over 9 taps per (pos,g) — 64 threads, in place
  if (t < 64){
    int p = t>>2, g = t&3;
    float* mr = raw + p*RS + 72 + g*9;
    float mx = -1e30f;
    for (int q=0;q<9;q++) mx = fmaxf(mx, mr[q]);
    float e[9]; float ssum=0.f;
    for (int q=0;q<9;q++){ e[q]=expf(mr[q]-mx); ssum+=e[q]; }
    float inv = 1.0f/ssum;
    for (int q=0;q<9;q++) mr[q] = e[q]*inv;
  }
  __syncthreads();

  // phase 3b: tap descriptors — 576 taps, mask premultiplied, OOB -> weight 0 + clamped offset
  for (int it=0; it<3; it++){
    int tid = t + 256*it;
    if (tid < 576){
      int pp = tid/36, rem = tid - pp*36;
      int g = rem/9, p = rem - g*9;
      int i = p/3, j = p - i*3;   // dx = ks[i], dy = ks[j] (torch meshgrid 'ij')
      float ox = raw[pp*RS + 2*(g*9+p)];
      float oy = raw[pp*RS + 2*(g*9+p)+1];
      float mval = raw[pp*RS + 72 + g*9 + p];
      float px = (float)(w0 + pp + i - 1) + ox;
      float py = (float)(h + j - 1) + oy;
      float fx0 = floorf(px), fy0 = floorf(py);
      int ix0 = (int)fx0, iy0 = (int)fy0;
      float fx = px - fx0, fy = py - fy0;
      float vx0 = ((unsigned)ix0     < 128u) ? 1.f : 0.f;
      float vx1 = ((unsigned)(ix0+1) < 128u) ? 1.f : 0.f;
      float vy0 = ((unsigned)iy0     < 128u) ? 1.f : 0.f;
      float vy1 = ((unsigned)(iy0+1) < 128u) ? 1.f : 0.f;
      int cx0 = min(max(ix0,0),127), cx1 = min(max(ix0+1,0),127);
      int cy0 = min(max(iy0,0),127), cy1 = min(max(iy0+1,0),127);
      float* d = desc + tid*8;
      d[0] = (1.f-fx)*(1.f-fy)*mval*vx0*vy0;
      d[1] = fx*(1.f-fy)*mval*vx1*vy0;
      d[2] = (1.f-fx)*fy*mval*vx0*vy1;
      d[3] = fx*fy*mval*vx1*vy1;
      *(int*)(d+4) = (cy0*128+cx0)*128;
      *(int*)(d+5) = (cy0*128+cx1)*128;
      *(int*)(d+6) = (cy1*128+cx0)*128;
      *(int*)(d+7) = (cy1*128+cx1)*128;
    }
  }
  __syncthreads();

  // phase 4: sampling — thread owns (pos = t>>4, channels ch0..ch0+7), group g = (t&15)>>2
  {
    int pp = t>>4, l = t&15;
    int ch0 = l*8, g = l>>2;
    const ushort_t* ib = x1 + imgbase + ch0;
    float acc[8];
    #pragma unroll
    for (int j=0;j<8;j++) acc[j]=0.f;
    const float* dbase = desc + (pp*36 + g*9)*8;
    #pragma unroll
    for (int p=0;p<9;p++){
      const float* d = dbase + p*8;
      float4 wv = *(const float4*)(d);
      int4  ov = *(const int4*)(d+4);
      ushort8v v00 = *(const ushort8v*)(ib + ov.x);
      ushort8v v10 = *(const ushort8v*)(ib + ov.y);
      ushort8v v01 = *(const ushort8v*)(ib + ov.z);
      ushort8v v11 = *(const ushort8v*)(ib + ov.w);
      #pragma unroll
      for (int j=0;j<8;j++){
        float s = wv.x*b2f(v00[j]) + wv.y*b2f(v10[j]) + wv.z*b2f(v01[j]) + wv.w*b2f(v11[j]);
        acc[j] += s;
      }
    }
    ushort8v outv;
    #pragma unroll
    for (int j=0;j<8;j++) outv[j] = f2b(acc[j]);
    *(ushort8v*)(dcnout + (size_t)(pos0+pp)*128 + ch0) = outv;
  }
}

// ---------------- kE: outproj + residual -> x2 (bf16); x is NCHW fp32 ----------------
__global__ __launch_bounds__(256) void kE_outproj(const ushort_t* __restrict__ dcnout,
    const float* __restrict__ pw, const float* __restrict__ pb,
    const float* __restrict__ x, ushort_t* __restrict__ x2){
  __shared__ __align__(16) float dt[16*128];
  __shared__ float xres[128*17];
  int t = threadIdx.x;
  int pos0 = blockIdx.x*16;
  int n = pos0>>14, hw0 = pos0&16383;
  for (int i=0;i<8;i++){
    int e = i*256+t;
    dt[e] = b2f(dcnout[(size_t)pos0*128 + e]);
  }
  const float* xb = x + (size_t)n*128*HWsz + hw0;
  for (int i=0;i<8;i++){
    int e = i*256+t;
    int c = e>>4, p = e&15;
    xres[c*17+p] = xb[(size_t)c*HWsz + p];
  }
  __syncthreads();
  int c = t&127, ph = t>>7;
  float acc[8];
  #pragma unroll
  for (int j=0;j<8;j++) acc[j]=0.f;
  const float* wrow = pw + c*128;
  for (int k=0;k<128;k+=4){
    const float4 wv = *(const float4*)(wrow+k);
    #pragma unroll
    for (int j=0;j<8;j++){
      const float4 xv = *(const float4*)(dt + (ph*8+j)*128 + k);
      acc[j] += wv.x*xv.x+wv.y*xv.y+wv.z*xv.z+wv.w*xv.w;
    }
  }
  float bias = pb[c];
  for (int j=0;j<8;j++){
    int p = ph*8+j;
    x2[(size_t)(pos0+p)*128+c] = f2b(acc[j] + bias + xres[c*17+p]);
  }
}

// ---------------- kFG: fused LN2 + MFMA MLP 128->512(gelu)->128 ----------------
__global__ __launch_bounds__(256) void kFG_mfma(const ushort_t* __restrict__ x2,
    const float* __restrict__ n2w, const float* __restrict__ n2b,
    const ushort_t* __restrict__ w1b, const float* __restrict__ b1,
    const ushort_t* __restrict__ w2b, const float* __restrict__ b2,
    ushort_t* __restrict__ mlpout){
  __shared__ __align__(16) ushort_t yln[16*128];
  __shared__ __align__(16) ushort_t hid[16*512];
  __shared__ float part[16*34];
  __shared__ float ms[16], rs[16];
  int t = threadIdx.x;
  int pos0 = blockIdx.x*16;

  float vals[8];
  {
    int tg = t>>4, l = t&15;
    float s=0.f, q=0.f;
    for (int j=0;j<8;j++){
      float v = b2f(x2[(size_t)(pos0+tg)*128 + l*8 + j]);
      vals[j]=v; s+=v; q+=v*v;
    }
    part[tg*34 + l] = s; part[tg*34 + 17 + l] = q;
  }
  __syncthreads();
  if (t < 16){
    float s=0.f, q=0.f;
    for (int l=0;l<16;l++){ s += part[t*34+l]; q += part[t*34+17+l]; }
    float m = s*(1.0f/128.0f);
    float var = q*(1.0f/128.0f) - m*m;
    ms[t]=m; rs[t]=rsqrtf(var+1e-6f);
  }
  __syncthreads();
  {
    int tg = t>>4, l = t&15;
    float m = ms[tg], r = rs[tg];
    for (int j=0;j<8;j++){
      int c = l*8+j;
      yln[tg*128 + c] = f2b((vals[j]-m)*r*n2w[c] + n2b[c]);
    }
  }
  __syncthreads();

  int wave = t>>6, lane = t&63;
  int ma = lane&15, quad = lane>>4;

  short8 afrag[4];
  #pragma unroll
  for (int ks=0; ks<4; ks++)
    afrag[ks] = *(const short8*)(yln + ma*128 + ks*32 + quad*8);
  f32x4 acc[8];
  #pragma unroll
  for (int i=0;i<8;i++) acc[i] = (f32x4){0.f,0.f,0.f,0.f};
  int nbase = wave*128;
  #pragma unroll
  for (int tile=0; tile<8; tile++){
    const ushort_t* brow = w1b + (size_t)(nbase + tile*16 + ma)*128 + quad*8;
    #pragma unroll
    for (int ks=0; ks<4; ks++){
      short8 bfrag = *(const short8*)(brow + ks*32);
      acc[tile] = __builtin_amdgcn_mfma_f32_16x16x32_bf16(afrag[ks], bfrag, acc[tile], 0,0,0);
    }
  }
  #pragma unroll
  for (int tile=0; tile<8; tile++){
    int nn = nbase + tile*16 + ma;
    float bias = b1[nn];
    #pragma unroll
    for (int r=0;r<4;r++){
      int m = quad*4 + r;
      hid[m*512 + nn] = f2b(gelu_exact(acc[tile][r] + bias));
    }
  }
  __syncthreads();

  f32x4 acc2[2];
  acc2[0] = (f32x4){0.f,0.f,0.f,0.f};
  acc2[1] = (f32x4){0.f,0.f,0.f,0.f};
  for (int ks=0; ks<16; ks++){
    short8 af = *(const short8*)(hid + ma*512 + ks*32 + quad*8);
    #pragma unroll
    for (int tile=0; tile<2; tile++){
      int c0 = wave*32 + tile*16;
      short8 bf = *(const short8*)(w2b + (size_t)(c0 + ma)*512 + ks*32 + quad*8);
      acc2[tile] = __builtin_amdgcn_mfma_f32_16x16x32_bf16(af, bf, acc2[tile], 0,0,0);
    }
  }
  #pragma unroll
  for (int tile=0; tile<2; tile++){
    int c = wave*32 + tile*16 + ma;
    float bias = b2[c];
    #pragma unroll
    for (int r=0;r<4;r++){
      int m = quad*4 + r;
      mlpout[(size_t)(pos0+m)*128 + c] = f2b(acc2[tile][r] + bias);
    }
  }
}

// ---------------- kH: final residual add + NHWC->NCHW fp32 out ----------------
__global__ __launch_bounds__(256) void kH_final(const ushort_t* __restrict__ x2,
    const ushort_t* __restrict__ mlpout, float* __restrict__ out){
  __shared__ float tile[64*130];
  int t = threadIdx.x;
  int pos0 = blockIdx.x*64;
  int n = pos0>>14, hw0 = pos0&16383;
  for (int i=0;i<32;i++){
    int e = i*256+t;
    int p = e>>7, c = e&127;
    tile[p*130+c] = b2f(x2[(size_t)pos0*128+e]) + b2f(mlpout[(size_t)pos0*128+e]);
  }
  __syncthreads();
  float* ob = out + (size_t)n*128*HWsz + hw0;
  for (int i=0;i<32;i++){
    int e = i*256+t;
    int c = e>>6, p = e&63;
    ob[(size_t)c*HWsz + p] = tile[p*130+c];
  }
}

extern "C" void kernel_launch(void* const* d_in, const int* in_sizes, int n_in,
                              void* d_out, int out_size, void* d_ws, size_t ws_size,
                              hipStream_t stream){
  const float* x     = (const float*)d_in[0];
  const float* n1w   = (const float*)d_in[1];
  const float* n1b   = (const float*)d_in[2];
  const float* dww   = (const float*)d_in[3];
  const float* dwb   = (const float*)d_in[4];
  const float* dwlnw = (const float*)d_in[5];
  const float* dwlnb = (const float*)d_in[6];
  const float* offw  = (const float*)d_in[7];
  const float* offb  = (const float*)d_in[8];
  const float* maskw = (const float*)d_in[9];
  const float* maskb = (const float*)d_in[10];
  const float* pw    = (const float*)d_in[11];
  const float* pb    = (const float*)d_in[12];
  const float* n2w   = (const float*)d_in[13];
  const float* n2b   = (const float*)d_in[14];
  const float* w1    = (const float*)d_in[15];
  const float* b1    = (const float*)d_in[16];
  const float* w2    = (const float*)d_in[17];
  const float* b2    = (const float*)d_in[18];

  // ws layout:
  //  R0 = ws[ 0,16MB): xcl (kA->kB) -> dcnout (kCD->kE) -> mlpout (kFG->kH)
  //  R1 = ws[16,32MB): x1  (kB->kCD) -> x2 (kE->kFG,kH)
  //  +32MB: w1b (128KB), w2b (128KB), owmb (32KB) all bf16
  char* wsb = (char*)d_ws;
  ushort_t* R0   = (ushort_t*)(wsb);
  ushort_t* R1   = (ushort_t*)(wsb + (16u<<20));
  ushort_t* w1b  = (ushort_t*)(wsb + (32u<<20));
  ushort_t* w2b  = (ushort_t*)(wsb + (32u<<20) + (128u<<10));
  ushort_t* owmb = (ushort_t*)(wsb + (32u<<20) + (256u<<10));
  float* out = (float*)d_out;

  hipLaunchKernelGGL(kW_cvt,  dim3(256),   dim3(256), 0, stream, w1, w2, offw, maskw, w1b, w2b, owmb);
  hipLaunchKernelGGL(kA_ln1,  dim3(1024),  dim3(256), 0, stream, x, n1w, n1b, R0);
  hipLaunchKernelGGL(kB_dw,   dim3(65536), dim3(128), 0, stream, R0, dww, dwb, dwlnw, dwlnb, R1);
  hipLaunchKernelGGL(kCD_dcn, dim3(4096),  dim3(256), 0, stream, R1, owmb, offb, maskb, R0);
  hipLaunchKernelGGL(kE_outproj, dim3(4096), dim3(256), 0, stream, R0, pw, pb, x, R1);
  hipLaunchKernelGGL(kFG_mfma, dim3(4096), dim3(256), 0, stream, R1, n2w, n2b, w1b, b1, w2b, b2, R0);
  hipLaunchKernelGGL(kH_final, dim3(1024), dim3(256), 0, stream, R1, R0, out);
}

// Round 7
// 450.667 us; speedup vs baseline: 2.7820x; 1.0050x over previous
//
#include <hip/hip_runtime.h>

typedef unsigned short ushort_t;
typedef short short8 __attribute__((ext_vector_type(8)));
typedef float f32x4 __attribute__((ext_vector_type(4)));
typedef ushort_t ushort8v __attribute__((ext_vector_type(8)));

#define HWsz 16384
#define NHWsz 65536
// padded LDS row strides (ushorts): 136*2=272B -> start bank 4*ma mod 32 (2-way, free)
#define YS 136
#define HS 520

__device__ __forceinline__ float b2f(ushort_t u){ return __uint_as_float(((unsigned)u)<<16); }
__device__ __forceinline__ ushort_t f2b(float f){
  unsigned x = __float_as_uint(f);
  x += 0x7fffu + ((x>>16)&1u);
  return (ushort_t)(x>>16);
}
__device__ __forceinline__ float gelu_exact(float x){
  return 0.5f*x*(1.0f+erff(x*0.70710678118654752f));
}

// ---------------- kW: convert weights fp32 -> bf16 (once per launch) ----------------
__global__ __launch_bounds__(256) void kW_cvt(const float* __restrict__ w1, const float* __restrict__ w2,
    const float* __restrict__ offw, const float* __restrict__ maskw,
    ushort_t* __restrict__ w1b, ushort_t* __restrict__ w2b, ushort_t* __restrict__ owmb){
  int i = blockIdx.x*256 + threadIdx.x;   // 65536
  w1b[i] = f2b(w1[i]);
  w2b[i] = f2b(w2[i]);
  if (i < 16384){
    int row = i >> 7, k = i & 127;
    float v = 0.f;
    if (row < 72) v = offw[row*128 + k];
    else if (row < 108) v = maskw[(row-72)*128 + k];
    owmb[i] = f2b(v);
  }
}

// ---------------- kA: LN1, NCHW fp32 -> NHWC bf16 ----------------
__global__ __launch_bounds__(256) void kA_ln1(const float* __restrict__ x,
    const float* __restrict__ w, const float* __restrict__ b,
    ushort_t* __restrict__ xcl){
  __shared__ float tile[128*66];
  __shared__ float psum[256], psq[256];
  __shared__ float ms[64], rs[64];
  int t = threadIdx.x;
  int pos0 = blockIdx.x * 64;
  int n = pos0 >> 14, hw0 = pos0 & 16383;
  const float* xb = x + (size_t)n*128*HWsz + hw0;
  for (int i=0;i<32;i++){
    int e = i*256+t;
    int c = e>>6, p = e&63;
    tile[c*66+p] = xb[(size_t)c*HWsz + p];
  }
  __syncthreads();
  {
    int part = t>>6, p = t&63;
    float s=0.f, q=0.f;
    for (int c=part*32; c<part*32+32; c++){ float v = tile[c*66+p]; s+=v; q+=v*v; }
    psum[part*64+p]=s; psq[part*64+p]=q;
  }
  __syncthreads();
  if (t<64){
    float s=psum[t]+psum[64+t]+psum[128+t]+psum[192+t];
    float q=psq[t]+psq[64+t]+psq[128+t]+psq[192+t];
    float m = s*(1.0f/128.0f);
    float v = q*(1.0f/128.0f)-m*m;
    ms[t]=m; rs[t]=rsqrtf(v+1e-6f);
  }
  __syncthreads();
  for (int i=0;i<32;i++){
    int e = i*256+t;
    int p = e>>7, c = e&127;
    float v = (tile[c*66+p]-ms[p])*rs[p]*w[c]+b[c];
    xcl[(size_t)(pos0+p)*128 + c] = f2b(v);
  }
}

// ---------------- kB: depthwise 3x3 + bias + LN + GELU ----------------
__global__ __launch_bounds__(128) void kB_dw(const ushort_t* __restrict__ xcl,
    const float* __restrict__ dww, const float* __restrict__ dwb,
    const float* __restrict__ lnw, const float* __restrict__ lnb,
    ushort_t* __restrict__ x1){
  __shared__ float red[128];
  int t = threadIdx.x;
  int pos = blockIdx.x;
  int n = pos>>14, hw = pos & 16383, h = hw>>7, w = hw&127;
  float acc = dwb[t];
  #pragma unroll
  for (int kh=0; kh<3; kh++){
    int hy = h + kh - 1;
    if ((unsigned)hy < 128u){
      #pragma unroll
      for (int kw=0; kw<3; kw++){
        int wx = w + kw - 1;
        if ((unsigned)wx < 128u){
          acc += b2f(xcl[((size_t)(n*16384 + hy*128 + wx))*128 + t]) * dww[t*9+kh*3+kw];
        }
      }
    }
  }
  red[t] = acc;
  __syncthreads();
  for (int s=64; s>0; s>>=1){ if (t<s) red[t]+=red[t+s]; __syncthreads(); }
  float m = red[0]*(1.0f/128.0f);
  __syncthreads();
  red[t] = acc*acc;
  __syncthreads();
  for (int s=64; s>0; s>>=1){ if (t<s) red[t]+=red[t+s]; __syncthreads(); }
  float var = red[0]*(1.0f/128.0f) - m*m;
  float r = rsqrtf(var+1e-6f);
  float v = (acc-m)*r*lnw[t]+lnb[t];
  x1[(size_t)pos*128 + t] = f2b(gelu_exact(v));
}

// ---------------- kCD: MFMA offset/mask + softmax + descriptor + vectorized sampling ----
#define RS 120
__global__ __launch_bounds__(256) void kCD_dcn(const ushort_t* __restrict__ x1,
    const ushort_t* __restrict__ owmb, const float* __restrict__ offb,
    const float* __restrict__ mb, ushort_t* __restrict__ dcnout){
  __shared__ __align__(16) ushort_t xLb[16*YS];    // bf16 A-tile, padded stride
  __shared__ float raw[16*RS];
  __shared__ __align__(16) float descW[576*4];
  __shared__ __align__(16) int   descO[576*4];
  int t = threadIdx.x;
  int pos0 = blockIdx.x*16;
  int n = pos0>>14, hw0 = pos0&16383, h = hw0>>7, w0 = hw0&127;
  const size_t imgbase = (size_t)n*16384*128;

  // phase 1: stage x1 tile
  *(ushort8v*)(xLb + (t>>4)*YS + (t&15)*8) = *(const ushort8v*)(x1 + (size_t)pos0*128 + t*8);
  __syncthreads();

  // phase 2: MFMA linear — rows 0..111
  {
    int wave = t>>6, lane = t&63;
    int ma = lane&15, quad = lane>>4;
    short8 afrag[4];
    #pragma unroll
    for (int ks=0; ks<4; ks++)
      afrag[ks] = *(const short8*)(xLb + ma*YS + ks*32 + quad*8);
    f32x4 acc[2];
    acc[0] = (f32x4){0.f,0.f,0.f,0.f};
    acc[1] = (f32x4){0.f,0.f,0.f,0.f};
    #pragma unroll
    for (int tile=0; tile<2; tile++){
      const ushort_t* brow = owmb + (size_t)(wave*32 + tile*16 + ma)*128 + quad*8;
      #pragma unroll
      for (int ks=0; ks<4; ks++){
        short8 bfrag = *(const short8*)(brow + ks*32);
        acc[tile] = __builtin_amdgcn_mfma_f32_16x16x32_bf16(afrag[ks], bfrag, acc[tile], 0,0,0);
      }
    }
    #pragma unroll
    for (int tile=0; tile<2; tile++){
      int row = wave*32 + tile*16 + ma;
      if (row < 112){
        float bias = (row < 72) ? offb[row] : ((row < 108) ? mb[row-72] : 0.f);
        #pragma unroll
        for (int r=0;r<4;r++){
          int m = quad*4 + r;
          raw[m*RS + row] = acc[tile][r] + bias;
        }
      }
    }
  }
  __syncthreads();

  // phase 3a: softmax over 9 taps per (pos,g)
  if (t < 64){
    int p = t>>2, g = t&3;
    float* mr = raw + p*RS + 72 + g*9;
    float mx = -1e30f;
    for (int q=0;q<9;q++) mx = fmaxf(mx, mr[q]);
    float e[9]; float ssum=0.f;
    for (int q=0;q<9;q++){ e[q]=expf(mr[q]-mx); ssum+=e[q]; }
    float inv = 1.0f/ssum;
    for (int q=0;q<9;q++) mr[q] = e[q]*inv;
  }
  __syncthreads();

  // phase 3b: tap descriptors
  for (int it=0; it<3; it++){
    int tid = t + 256*it;
    if (tid < 576){
      int pp = tid/36, rem = tid - pp*36;
      int g = rem/9, p = rem - g*9;
      int i = p/3, j = p - i*3;   // dx = ks[i], dy = ks[j]
      float ox = raw[pp*RS + 2*(g*9+p)];
      float oy = raw[pp*RS + 2*(g*9+p)+1];
      float mval = raw[pp*RS + 72 + g*9 + p];
      float px = (float)(w0 + pp + i - 1) + ox;
      float py = (float)(h + j - 1) + oy;
      float fx0 = floorf(px), fy0 = floorf(py);
      int ix0 = (int)fx0, iy0 = (int)fy0;
      float fx = px - fx0, fy = py - fy0;
      float vx0 = ((unsigned)ix0     < 128u) ? 1.f : 0.f;
      float vx1 = ((unsigned)(ix0+1) < 128u) ? 1.f : 0.f;
      float vy0 = ((unsigned)iy0     < 128u) ? 1.f : 0.f;
      float vy1 = ((unsigned)(iy0+1) < 128u) ? 1.f : 0.f;
      int cx0 = min(max(ix0,0),127), cx1 = min(max(ix0+1,0),127);
      int cy0 = min(max(iy0,0),127), cy1 = min(max(iy0+1,0),127);
      float4 wv;
      wv.x = (1.f-fx)*(1.f-fy)*mval*vx0*vy0;
      wv.y = fx*(1.f-fy)*mval*vx1*vy0;
      wv.z = (1.f-fx)*fy*mval*vx0*vy1;
      wv.w = fx*fy*mval*vx1*vy1;
      int4 ov;
      ov.x = (cy0*128+cx0)*128;
      ov.y = (cy0*128+cx1)*128;
      ov.z = (cy1*128+cx0)*128;
      ov.w = (cy1*128+cx1)*128;
      *(float4*)(descW + tid*4) = wv;
      *(int4*)(descO + tid*4) = ov;
    }
  }
  __syncthreads();

  // phase 4: sampling — thread owns (pos = t>>4, 8 channels), group g = (t&15)>>2
  {
    int pp = t>>4, l = t&15;
    int ch0 = l*8, g = l>>2;
    const ushort_t* ib = x1 + imgbase + ch0;
    float acc[8];
    #pragma unroll
    for (int j=0;j<8;j++) acc[j]=0.f;
    int dbase = pp*36 + g*9;
    #pragma unroll
    for (int p=0;p<9;p++){
      float4 wv = *(const float4*)(descW + (dbase+p)*4);
      int4  ov = *(const int4*)(descO + (dbase+p)*4);
      ushort8v v00 = *(const ushort8v*)(ib + ov.x);
      ushort8v v10 = *(const ushort8v*)(ib + ov.y);
      ushort8v v01 = *(const ushort8v*)(ib + ov.z);
      ushort8v v11 = *(const ushort8v*)(ib + ov.w);
      #pragma unroll
      for (int j=0;j<8;j++){
        float s = wv.x*b2f(v00[j]) + wv.y*b2f(v10[j]) + wv.z*b2f(v01[j]) + wv.w*b2f(v11[j]);
        acc[j] += s;
      }
    }
    ushort8v outv;
    #pragma unroll
    for (int j=0;j<8;j++) outv[j] = f2b(acc[j]);
    *(ushort8v*)(dcnout + (size_t)(pos0+pp)*128 + ch0) = outv;
  }
}

// ---------------- kE: outproj + residual -> x2 (bf16); x is NCHW fp32 ----------------
__global__ __launch_bounds__(256) void kE_outproj(const ushort_t* __restrict__ dcnout,
    const float* __restrict__ pw, const float* __restrict__ pb,
    const float* __restrict__ x, ushort_t* __restrict__ x2){
  __shared__ __align__(16) float dt[16*128];
  __shared__ float xres[128*17];
  int t = threadIdx.x;
  int pos0 = blockIdx.x*16;
  int n = pos0>>14, hw0 = pos0&16383;
  for (int i=0;i<8;i++){
    int e = i*256+t;
    dt[e] = b2f(dcnout[(size_t)pos0*128 + e]);
  }
  const float* xb = x + (size_t)n*128*HWsz + hw0;
  for (int i=0;i<8;i++){
    int e = i*256+t;
    int c = e>>4, p = e&15;
    xres[c*17+p] = xb[(size_t)c*HWsz + p];
  }
  __syncthreads();
  int c = t&127, ph = t>>7;
  float acc[8];
  #pragma unroll
  for (int j=0;j<8;j++) acc[j]=0.f;
  const float* wrow = pw + c*128;
  for (int k=0;k<128;k+=4){
    const float4 wv = *(const float4*)(wrow+k);
    #pragma unroll
    for (int j=0;j<8;j++){
      const float4 xv = *(const float4*)(dt + (ph*8+j)*128 + k);
      acc[j] += wv.x*xv.x+wv.y*xv.y+wv.z*xv.z+wv.w*xv.w;
    }
  }
  float bias = pb[c];
  for (int j=0;j<8;j++){
    int p = ph*8+j;
    x2[(size_t)(pos0+p)*128+c] = f2b(acc[j] + bias + xres[c*17+p]);
  }
}

// ---------------- kFG: fused LN2 + MFMA MLP 128->512(gelu)->128 ----------------
__global__ __launch_bounds__(256) void kFG_mfma(const ushort_t* __restrict__ x2,
    const float* __restrict__ n2w, const float* __restrict__ n2b,
    const ushort_t* __restrict__ w1b, const float* __restrict__ b1,
    const ushort_t* __restrict__ w2b, const float* __restrict__ b2,
    ushort_t* __restrict__ mlpout){
  __shared__ __align__(16) ushort_t yln[16*YS];
  __shared__ __align__(16) ushort_t hid[16*HS];
  __shared__ float part[16*34];
  __shared__ float ms[16], rs[16];
  int t = threadIdx.x;
  int pos0 = blockIdx.x*16;

  // --- LN2 (thread: position t>>4, 8 contiguous channels) ---
  float vals[8];
  {
    int tg = t>>4, l = t&15;
    ushort8v xv = *(const ushort8v*)(x2 + (size_t)(pos0+tg)*128 + l*8);
    float s=0.f, q=0.f;
    #pragma unroll
    for (int j=0;j<8;j++){ float v = b2f(xv[j]); vals[j]=v; s+=v; q+=v*v; }
    part[tg*34 + l] = s; part[tg*34 + 17 + l] = q;
  }
  __syncthreads();
  if (t < 16){
    float s=0.f, q=0.f;
    for (int l=0;l<16;l++){ s += part[t*34+l]; q += part[t*34+17+l]; }
    float m = s*(1.0f/128.0f);
    float var = q*(1.0f/128.0f) - m*m;
    ms[t]=m; rs[t]=rsqrtf(var+1e-6f);
  }
  __syncthreads();
  {
    int tg = t>>4, l = t&15;
    float m = ms[tg], r = rs[tg];
    ushort8v yv;
    #pragma unroll
    for (int j=0;j<8;j++){
      int c = l*8+j;
      yv[j] = f2b((vals[j]-m)*r*n2w[c] + n2b[c]);
    }
    *(ushort8v*)(yln + tg*YS + l*8) = yv;
  }
  __syncthreads();

  int wave = t>>6, lane = t&63;
  int ma = lane&15, quad = lane>>4;

  // --- FC1: wave covers n in [wave*128, wave*128+128), K=128 ---
  short8 afrag[4];
  #pragma unroll
  for (int ks=0; ks<4; ks++)
    afrag[ks] = *(const short8*)(yln + ma*YS + ks*32 + quad*8);
  f32x4 acc[8];
  #pragma unroll
  for (int i=0;i<8;i++) acc[i] = (f32x4){0.f,0.f,0.f,0.f};
  int nbase = wave*128;
  #pragma unroll
  for (int tile=0; tile<8; tile++){
    const ushort_t* brow = w1b + (size_t)(nbase + tile*16 + ma)*128 + quad*8;
    #pragma unroll
    for (int ks=0; ks<4; ks++){
      short8 bfrag = *(const short8*)(brow + ks*32);
      acc[tile] = __builtin_amdgcn_mfma_f32_16x16x32_bf16(afrag[ks], bfrag, acc[tile], 0,0,0);
    }
  }
  #pragma unroll
  for (int tile=0; tile<8; tile++){
    int nn = nbase + tile*16 + ma;
    float bias = b1[nn];
    #pragma unroll
    for (int r=0;r<4;r++){
      int m = quad*4 + r;
      hid[m*HS + nn] = f2b(gelu_exact(acc[tile][r] + bias));
    }
  }
  __syncthreads();

  // --- FC2: wave covers c in [wave*32, wave*32+32), K=512 ---
  f32x4 acc2[2];
  acc2[0] = (f32x4){0.f,0.f,0.f,0.f};
  acc2[1] = (f32x4){0.f,0.f,0.f,0.f};
  for (int ks=0; ks<16; ks++){
    short8 af = *(const short8*)(hid + ma*HS + ks*32 + quad*8);
    #pragma unroll
    for (int tile=0; tile<2; tile++){
      int c0 = wave*32 + tile*16;
      short8 bf = *(const short8*)(w2b + (size_t)(c0 + ma)*512 + ks*32 + quad*8);
      acc2[tile] = __builtin_amdgcn_mfma_f32_16x16x32_bf16(af, bf, acc2[tile], 0,0,0);
    }
  }
  #pragma unroll
  for (int tile=0; tile<2; tile++){
    int c = wave*32 + tile*16 + ma;
    float bias = b2[c];
    #pragma unroll
    for (int r=0;r<4;r++){
      int m = quad*4 + r;
      mlpout[(size_t)(pos0+m)*128 + c] = f2b(acc2[tile][r] + bias);
    }
  }
}

// ---------------- kH: final residual add + NHWC->NCHW fp32 out ----------------
__global__ __launch_bounds__(256) void kH_final(const ushort_t* __restrict__ x2,
    const ushort_t* __restrict__ mlpout, float* __restrict__ out){
  __shared__ float tile[64*130];
  int t = threadIdx.x;
  int pos0 = blockIdx.x*64;
  int n = pos0>>14, hw0 = pos0&16383;
  for (int i=0;i<32;i++){
    int e = i*256+t;
    int p = e>>7, c = e&127;
    tile[p*130+c] = b2f(x2[(size_t)pos0*128+e]) + b2f(mlpout[(size_t)pos0*128+e]);
  }
  __syncthreads();
  float* ob = out + (size_t)n*128*HWsz + hw0;
  for (int i=0;i<32;i++){
    int e = i*256+t;
    int c = e>>6, p = e&63;
    ob[(size_t)c*HWsz + p] = tile[p*130+c];
  }
}

extern "C" void kernel_launch(void* const* d_in, const int* in_sizes, int n_in,
                              void* d_out, int out_size, void* d_ws, size_t ws_size,
                              hipStream_t stream){
  const float* x     = (const float*)d_in[0];
  const float* n1w   = (const float*)d_in[1];
  const float* n1b   = (const float*)d_in[2];
  const float* dww   = (const float*)d_in[3];
  const float* dwb   = (const float*)d_in[4];
  const float* dwlnw = (const float*)d_in[5];
  const float* dwlnb = (const float*)d_in[6];
  const float* offw  = (const float*)d_in[7];
  const float* offb  = (const float*)d_in[8];
  const float* maskw = (const float*)d_in[9];
  const float* maskb = (const float*)d_in[10];
  const float* pw    = (const float*)d_in[11];
  const float* pb    = (const float*)d_in[12];
  const float* n2w   = (const float*)d_in[13];
  const float* n2b   = (const float*)d_in[14];
  const float* w1    = (const float*)d_in[15];
  const float* b1    = (const float*)d_in[16];
  const float* w2    = (const float*)d_in[17];
  const float* b2    = (const float*)d_in[18];

  // ws layout:
  //  R0 = ws[ 0,16MB): xcl (kA->kB) -> dcnout (kCD->kE) -> mlpout (kFG->kH)
  //  R1 = ws[16,32MB): x1  (kB->kCD) -> x2 (kE->kFG,kH)
  //  +32MB: w1b (128KB), w2b (128KB), owmb (32KB) all bf16
  char* wsb = (char*)d_ws;
  ushort_t* R0   = (ushort_t*)(wsb);
  ushort_t* R1   = (ushort_t*)(wsb + (16u<<20));
  ushort_t* w1b  = (ushort_t*)(wsb + (32u<<20));
  ushort_t* w2b  = (ushort_t*)(wsb + (32u<<20) + (128u<<10));
  ushort_t* owmb = (ushort_t*)(wsb + (32u<<20) + (256u<<10));
  float* out = (float*)d_out;

  hipLaunchKernelGGL(kW_cvt,  dim3(256),   dim3(256), 0, stream, w1, w2, offw, maskw, w1b, w2b, owmb);
  hipLaunchKernelGGL(kA_ln1,  dim3(1024),  dim3(256), 0, stream, x, n1w, n1b, R0);
  hipLaunchKernelGGL(kB_dw,   dim3(65536), dim3(128), 0, stream, R0, dww, dwb, dwlnw, dwlnb, R1);
  hipLaunchKernelGGL(kCD_dcn, dim3(4096),  dim3(256), 0, stream, R1, owmb, offb, maskb, R0);
  hipLaunchKernelGGL(kE_outproj, dim3(4096), dim3(256), 0, stream, R0, pw, pb, x, R1);
  hipLaunchKernelGGL(kFG_mfma, dim3(4096), dim3(256), 0, stream, R1, n2w, n2b, w1b, b1, w2b, b2, R0);
  hipLaunchKernelGGL(kH_final, dim3(1024), dim3(256), 0, stream, R1, R0, out);
}

// Round 8
// 356.762 us; speedup vs baseline: 3.5142x; 1.2632x over previous
//
#include <hip/hip_runtime.h>

typedef unsigned short ushort_t;
typedef short short8 __attribute__((ext_vector_type(8)));
typedef float f32x4 __attribute__((ext_vector_type(4)));
typedef ushort_t ushort8v __attribute__((ext_vector_type(8)));

#define HWsz 16384
#define NHWsz 65536
// padded LDS row strides (ushorts): stride%128B != 0 -> start bank 4*ma mod 32 (2-way, free)
#define YS 136
#define HS 520

__device__ __forceinline__ float b2f(ushort_t u){ return __uint_as_float(((unsigned)u)<<16); }
__device__ __forceinline__ ushort_t f2b(float f){
  unsigned x = __float_as_uint(f);
  x += 0x7fffu + ((x>>16)&1u);
  return (ushort_t)(x>>16);
}
__device__ __forceinline__ float gelu_exact(float x){
  return 0.5f*x*(1.0f+erff(x*0.70710678118654752f));
}

// ---------------- kW: weight preprocessing (once per launch) ----------------
// w1/w2 -> bf16; offset/mask weights -> padded bf16 128x128 block; dwconv weights -> [k][c] fp32.
__global__ __launch_bounds__(256) void kW_cvt(const float* __restrict__ w1, const float* __restrict__ w2,
    const float* __restrict__ offw, const float* __restrict__ maskw, const float* __restrict__ dww,
    ushort_t* __restrict__ w1b, ushort_t* __restrict__ w2b, ushort_t* __restrict__ owmb,
    float* __restrict__ dwwT){
  int i = blockIdx.x*256 + threadIdx.x;   // 65536
  w1b[i] = f2b(w1[i]);
  w2b[i] = f2b(w2[i]);
  if (i < 16384){
    int row = i >> 7, k = i & 127;
    float v = 0.f;
    if (row < 72) v = offw[row*128 + k];
    else if (row < 108) v = maskw[(row-72)*128 + k];
    owmb[i] = f2b(v);
  }
  if (i < 1152){
    int k = i >> 7, c = i & 127;
    dwwT[i] = dww[c*9 + k];
  }
}

// ---------------- kA: LN1, NCHW fp32 -> NHWC bf16 ----------------
__global__ __launch_bounds__(256) void kA_ln1(const float* __restrict__ x,
    const float* __restrict__ w, const float* __restrict__ b,
    ushort_t* __restrict__ xcl){
  __shared__ float tile[128*66];
  __shared__ float psum[256], psq[256];
  __shared__ float ms[64], rs[64];
  int t = threadIdx.x;
  int pos0 = blockIdx.x * 64;
  int n = pos0 >> 14, hw0 = pos0 & 16383;
  const float* xb = x + (size_t)n*128*HWsz + hw0;
  for (int i=0;i<32;i++){
    int e = i*256+t;
    int c = e>>6, p = e&63;
    tile[c*66+p] = xb[(size_t)c*HWsz + p];
  }
  __syncthreads();
  {
    int part = t>>6, p = t&63;
    float s=0.f, q=0.f;
    for (int c=part*32; c<part*32+32; c++){ float v = tile[c*66+p]; s+=v; q+=v*v; }
    psum[part*64+p]=s; psq[part*64+p]=q;
  }
  __syncthreads();
  if (t<64){
    float s=psum[t]+psum[64+t]+psum[128+t]+psum[192+t];
    float q=psq[t]+psq[64+t]+psq[128+t]+psq[192+t];
    float m = s*(1.0f/128.0f);
    float v = q*(1.0f/128.0f)-m*m;
    ms[t]=m; rs[t]=rsqrtf(v+1e-6f);
  }
  __syncthreads();
  for (int i=0;i<32;i++){
    int e = i*256+t;
    int p = e>>7, c = e&127;
    float v = (tile[c*66+p]-ms[p])*rs[p]*w[c]+b[c];
    xcl[(size_t)(pos0+p)*128 + c] = f2b(v);
  }
}

// ---------------- kB v2: depthwise 3x3 + bias + LN + GELU ----------------
// 16 positions per 256-thread block; thread owns (pos, 8 channels); 16B loads; 2 barriers.
__global__ __launch_bounds__(256) void kB_dw(const ushort_t* __restrict__ xcl,
    const float* __restrict__ dwwT, const float* __restrict__ dwb,
    const float* __restrict__ lnw, const float* __restrict__ lnb,
    ushort_t* __restrict__ x1){
  __shared__ float partS[16*17], partQ[16*17];
  __shared__ float ms[16], rs[16];
  int t = threadIdx.x;
  int pos0 = blockIdx.x*16;
  int n = pos0>>14, hw0 = pos0&16383, h = hw0>>7, w0 = hw0&127;
  int pp = t>>4, l = t&15, ch0 = l*8;
  int w = w0 + pp;
  float acc[8];
  {
    float4 b0 = *(const float4*)(dwb + ch0);
    float4 b1 = *(const float4*)(dwb + ch0 + 4);
    acc[0]=b0.x; acc[1]=b0.y; acc[2]=b0.z; acc[3]=b0.w;
    acc[4]=b1.x; acc[5]=b1.y; acc[6]=b1.z; acc[7]=b1.w;
  }
  #pragma unroll
  for (int kh=0; kh<3; kh++){
    int hy = h + kh - 1;
    if ((unsigned)hy < 128u){
      #pragma unroll
      for (int kw=0; kw<3; kw++){
        int wx = w + kw - 1;
        if ((unsigned)wx < 128u){
          ushort8v xv = *(const ushort8v*)(xcl + ((size_t)(n*16384 + hy*128 + wx))*128 + ch0);
          const float* wr = dwwT + (kh*3+kw)*128 + ch0;
          float4 w0v = *(const float4*)(wr);
          float4 w1v = *(const float4*)(wr+4);
          acc[0] += b2f(xv[0])*w0v.x; acc[1] += b2f(xv[1])*w0v.y;
          acc[2] += b2f(xv[2])*w0v.z; acc[3] += b2f(xv[3])*w0v.w;
          acc[4] += b2f(xv[4])*w1v.x; acc[5] += b2f(xv[5])*w1v.y;
          acc[6] += b2f(xv[6])*w1v.z; acc[7] += b2f(xv[7])*w1v.w;
        }
      }
    }
  }
  {
    float s=0.f, q=0.f;
    #pragma unroll
    for (int j=0;j<8;j++){ s+=acc[j]; q+=acc[j]*acc[j]; }
    partS[pp*17+l]=s; partQ[pp*17+l]=q;
  }
  __syncthreads();
  if (t<16){
    float s=0.f, q=0.f;
    for (int i=0;i<16;i++){ s += partS[t*17+i]; q += partQ[t*17+i]; }
    float m = s*(1.0f/128.0f);
    float var = q*(1.0f/128.0f) - m*m;
    ms[t]=m; rs[t]=rsqrtf(var+1e-6f);
  }
  __syncthreads();
  {
    float m = ms[pp], r = rs[pp];
    float4 lw0 = *(const float4*)(lnw + ch0);
    float4 lw1 = *(const float4*)(lnw + ch0 + 4);
    float4 lb0 = *(const float4*)(lnb + ch0);
    float4 lb1 = *(const float4*)(lnb + ch0 + 4);
    float lw[8] = {lw0.x,lw0.y,lw0.z,lw0.w,lw1.x,lw1.y,lw1.z,lw1.w};
    float lb[8] = {lb0.x,lb0.y,lb0.z,lb0.w,lb1.x,lb1.y,lb1.z,lb1.w};
    ushort8v o;
    #pragma unroll
    for (int j=0;j<8;j++){
      float v = (acc[j]-m)*r*lw[j]+lb[j];
      o[j] = f2b(gelu_exact(v));
    }
    *(ushort8v*)(x1 + (size_t)(pos0+pp)*128 + ch0) = o;
  }
}

// ---------------- kCD: MFMA offset/mask + softmax + descriptor + vectorized sampling ----
#define RS 120
__global__ __launch_bounds__(256) void kCD_dcn(const ushort_t* __restrict__ x1,
    const ushort_t* __restrict__ owmb, const float* __restrict__ offb,
    const float* __restrict__ mb, ushort_t* __restrict__ dcnout){
  __shared__ __align__(16) ushort_t xLb[16*YS];
  __shared__ float raw[16*RS];
  __shared__ __align__(16) float descW[576*4];
  __shared__ __align__(16) int   descO[576*4];
  int t = threadIdx.x;
  int pos0 = blockIdx.x*16;
  int n = pos0>>14, hw0 = pos0&16383, h = hw0>>7, w0 = hw0&127;
  const size_t imgbase = (size_t)n*16384*128;

  *(ushort8v*)(xLb + (t>>4)*YS + (t&15)*8) = *(const ushort8v*)(x1 + (size_t)pos0*128 + t*8);
  __syncthreads();

  {
    int wave = t>>6, lane = t&63;
    int ma = lane&15, quad = lane>>4;
    short8 afrag[4];
    #pragma unroll
    for (int ks=0; ks<4; ks++)
      afrag[ks] = *(const short8*)(xLb + ma*YS + ks*32 + quad*8);
    f32x4 acc[2];
    acc[0] = (f32x4){0.f,0.f,0.f,0.f};
    acc[1] = (f32x4){0.f,0.f,0.f,0.f};
    #pragma unroll
    for (int tile=0; tile<2; tile++){
      const ushort_t* brow = owmb + (size_t)(wave*32 + tile*16 + ma)*128 + quad*8;
      #pragma unroll
      for (int ks=0; ks<4; ks++){
        short8 bfrag = *(const short8*)(brow + ks*32);
        acc[tile] = __builtin_amdgcn_mfma_f32_16x16x32_bf16(afrag[ks], bfrag, acc[tile], 0,0,0);
      }
    }
    #pragma unroll
    for (int tile=0; tile<2; tile++){
      int row = wave*32 + tile*16 + ma;
      if (row < 112){
        float bias = (row < 72) ? offb[row] : ((row < 108) ? mb[row-72] : 0.f);
        #pragma unroll
        for (int r=0;r<4;r++){
          int m = quad*4 + r;
          raw[m*RS + row] = acc[tile][r] + bias;
        }
      }
    }
  }
  __syncthreads();

  if (t < 64){
    int p = t>>2, g = t&3;
    float* mr = raw + p*RS + 72 + g*9;
    float mx = -1e30f;
    for (int q=0;q<9;q++) mx = fmaxf(mx, mr[q]);
    float e[9]; float ssum=0.f;
    for (int q=0;q<9;q++){ e[q]=expf(mr[q]-mx); ssum+=e[q]; }
    float inv = 1.0f/ssum;
    for (int q=0;q<9;q++) mr[q] = e[q]*inv;
  }
  __syncthreads();

  for (int it=0; it<3; it++){
    int tid = t + 256*it;
    if (tid < 576){
      int pp = tid/36, rem = tid - pp*36;
      int g = rem/9, p = rem - g*9;
      int i = p/3, j = p - i*3;
      float ox = raw[pp*RS + 2*(g*9+p)];
      float oy = raw[pp*RS + 2*(g*9+p)+1];
      float mval = raw[pp*RS + 72 + g*9 + p];
      float px = (float)(w0 + pp + i - 1) + ox;
      float py = (float)(h + j - 1) + oy;
      float fx0 = floorf(px), fy0 = floorf(py);
      int ix0 = (int)fx0, iy0 = (int)fy0;
      float fx = px - fx0, fy = py - fy0;
      float vx0 = ((unsigned)ix0     < 128u) ? 1.f : 0.f;
      float vx1 = ((unsigned)(ix0+1) < 128u) ? 1.f : 0.f;
      float vy0 = ((unsigned)iy0     < 128u) ? 1.f : 0.f;
      float vy1 = ((unsigned)(iy0+1) < 128u) ? 1.f : 0.f;
      int cx0 = min(max(ix0,0),127), cx1 = min(max(ix0+1,0),127);
      int cy0 = min(max(iy0,0),127), cy1 = min(max(iy0+1,0),127);
      float4 wv;
      wv.x = (1.f-fx)*(1.f-fy)*mval*vx0*vy0;
      wv.y = fx*(1.f-fy)*mval*vx1*vy0;
      wv.z = (1.f-fx)*fy*mval*vx0*vy1;
      wv.w = fx*fy*mval*vx1*vy1;
      int4 ov;
      ov.x = (cy0*128+cx0)*128;
      ov.y = (cy0*128+cx1)*128;
      ov.z = (cy1*128+cx0)*128;
      ov.w = (cy1*128+cx1)*128;
      *(float4*)(descW + tid*4) = wv;
      *(int4*)(descO + tid*4) = ov;
    }
  }
  __syncthreads();

  {
    int pp = t>>4, l = t&15;
    int ch0 = l*8, g = l>>2;
    const ushort_t* ib = x1 + imgbase + ch0;
    float acc[8];
    #pragma unroll
    for (int j=0;j<8;j++) acc[j]=0.f;
    int dbase = pp*36 + g*9;
    #pragma unroll
    for (int p=0;p<9;p++){
      float4 wv = *(const float4*)(descW + (dbase+p)*4);
      int4  ov = *(const int4*)(descO + (dbase+p)*4);
      ushort8v v00 = *(const ushort8v*)(ib + ov.x);
      ushort8v v10 = *(const ushort8v*)(ib + ov.y);
      ushort8v v01 = *(const ushort8v*)(ib + ov.z);
      ushort8v v11 = *(const ushort8v*)(ib + ov.w);
      #pragma unroll
      for (int j=0;j<8;j++){
        float s = wv.x*b2f(v00[j]) + wv.y*b2f(v10[j]) + wv.z*b2f(v01[j]) + wv.w*b2f(v11[j]);
        acc[j] += s;
      }
    }
    ushort8v outv;
    #pragma unroll
    for (int j=0;j<8;j++) outv[j] = f2b(acc[j]);
    *(ushort8v*)(dcnout + (size_t)(pos0+pp)*128 + ch0) = outv;
  }
}

// ---------------- kE: outproj + residual -> x2 (bf16); x is NCHW fp32 ----------------
__global__ __launch_bounds__(256) void kE_outproj(const ushort_t* __restrict__ dcnout,
    const float* __restrict__ pw, const float* __restrict__ pb,
    const float* __restrict__ x, ushort_t* __restrict__ x2){
  __shared__ __align__(16) float dt[16*128];
  __shared__ float xres[128*17];
  int t = threadIdx.x;
  int pos0 = blockIdx.x*16;
  int n = pos0>>14, hw0 = pos0&16383;
  for (int i=0;i<8;i++){
    int e = i*256+t;
    dt[e] = b2f(dcnout[(size_t)pos0*128 + e]);
  }
  const float* xb = x + (size_t)n*128*HWsz + hw0;
  for (int i=0;i<8;i++){
    int e = i*256+t;
    int c = e>>4, p = e&15;
    xres[c*17+p] = xb[(size_t)c*HWsz + p];
  }
  __syncthreads();
  int c = t&127, ph = t>>7;
  float acc[8];
  #pragma unroll
  for (int j=0;j<8;j++) acc[j]=0.f;
  const float* wrow = pw + c*128;
  for (int k=0;k<128;k+=4){
    const float4 wv = *(const float4*)(wrow+k);
    #pragma unroll
    for (int j=0;j<8;j++){
      const float4 xv = *(const float4*)(dt + (ph*8+j)*128 + k);
      acc[j] += wv.x*xv.x+wv.y*xv.y+wv.z*xv.z+wv.w*xv.w;
    }
  }
  float bias = pb[c];
  for (int j=0;j<8;j++){
    int p = ph*8+j;
    x2[(size_t)(pos0+p)*128+c] = f2b(acc[j] + bias + xres[c*17+p]);
  }
}

// ---------------- kFG v3: fused LN2 + MFMA MLP, 32 positions/block, 2 M-tiles/wave ----
__global__ __launch_bounds__(256) void kFG_mfma(const ushort_t* __restrict__ x2,
    const float* __restrict__ n2w, const float* __restrict__ n2b,
    const ushort_t* __restrict__ w1b, const float* __restrict__ b1,
    const ushort_t* __restrict__ w2b, const float* __restrict__ b2,
    ushort_t* __restrict__ mlpout){
  __shared__ __align__(16) ushort_t yln[32*YS];
  __shared__ __align__(16) ushort_t hid[32*HS];
  __shared__ float partS[32*9], partQ[32*9];
  __shared__ float ms[32], rs[32];
  int t = threadIdx.x;
  int pos0 = blockIdx.x*32;

  // --- LN2: thread owns (pos = t>>3, 16 channels c0=(t&7)*16) ---
  float vals[16];
  int tg = t>>3, li = t&7, c0 = li*16;
  {
    ushort8v xv0 = *(const ushort8v*)(x2 + (size_t)(pos0+tg)*128 + c0);
    ushort8v xv1 = *(const ushort8v*)(x2 + (size_t)(pos0+tg)*128 + c0 + 8);
    float s=0.f, q=0.f;
    #pragma unroll
    for (int j=0;j<8;j++){ float v=b2f(xv0[j]); vals[j]=v; s+=v; q+=v*v; }
    #pragma unroll
    for (int j=0;j<8;j++){ float v=b2f(xv1[j]); vals[8+j]=v; s+=v; q+=v*v; }
    partS[tg*9+li]=s; partQ[tg*9+li]=q;
  }
  __syncthreads();
  if (t < 32){
    float s=0.f, q=0.f;
    for (int i=0;i<8;i++){ s += partS[t*9+i]; q += partQ[t*9+i]; }
    float m = s*(1.0f/128.0f);
    float var = q*(1.0f/128.0f) - m*m;
    ms[t]=m; rs[t]=rsqrtf(var+1e-6f);
  }
  __syncthreads();
  {
    float m = ms[tg], r = rs[tg];
    ushort8v y0, y1;
    #pragma unroll
    for (int j=0;j<8;j++){
      int c = c0+j;
      y0[j] = f2b((vals[j]-m)*r*n2w[c] + n2b[c]);
    }
    #pragma unroll
    for (int j=0;j<8;j++){
      int c = c0+8+j;
      y1[j] = f2b((vals[8+j]-m)*r*n2w[c] + n2b[c]);
    }
    *(ushort8v*)(yln + tg*YS + c0)     = y0;
    *(ushort8v*)(yln + tg*YS + c0 + 8) = y1;
  }
  __syncthreads();

  int wave = t>>6, lane = t&63;
  int ma = lane&15, quad = lane>>4;

  // --- FC1: wave covers n in [wave*128, wave*128+128); 2 M-tiles (pos 0..15, 16..31) ---
  short8 af[2][4];
  #pragma unroll
  for (int mt=0; mt<2; mt++)
    #pragma unroll
    for (int ks=0; ks<4; ks++)
      af[mt][ks] = *(const short8*)(yln + (mt*16+ma)*YS + ks*32 + quad*8);
  f32x4 acc[8][2];
  #pragma unroll
  for (int i=0;i<8;i++){ acc[i][0] = (f32x4){0.f,0.f,0.f,0.f}; acc[i][1] = (f32x4){0.f,0.f,0.f,0.f}; }
  int nbase = wave*128;
  #pragma unroll
  for (int tile=0; tile<8; tile++){
    const ushort_t* brow = w1b + (size_t)(nbase + tile*16 + ma)*128 + quad*8;
    short8 bf[4];
    #pragma unroll
    for (int ks=0; ks<4; ks++) bf[ks] = *(const short8*)(brow + ks*32);
    #pragma unroll
    for (int mt=0; mt<2; mt++)
      #pragma unroll
      for (int ks=0; ks<4; ks++)
        acc[tile][mt] = __builtin_amdgcn_mfma_f32_16x16x32_bf16(af[mt][ks], bf[ks], acc[tile][mt], 0,0,0);
  }
  #pragma unroll
  for (int tile=0; tile<8; tile++){
    int nn = nbase + tile*16 + ma;
    float bias = b1[nn];
    #pragma unroll
    for (int mt=0; mt<2; mt++)
      #pragma unroll
      for (int r=0;r<4;r++){
        int m = mt*16 + quad*4 + r;
        hid[m*HS + nn] = f2b(gelu_exact(acc[tile][mt][r] + bias));
      }
  }
  __syncthreads();

  // --- FC2: wave covers c in [wave*32, wave*32+32); 2 M-tiles; K=512 ---
  f32x4 acc2[2][2];
  acc2[0][0] = (f32x4){0.f,0.f,0.f,0.f}; acc2[0][1] = (f32x4){0.f,0.f,0.f,0.f};
  acc2[1][0] = (f32x4){0.f,0.f,0.f,0.f}; acc2[1][1] = (f32x4){0.f,0.f,0.f,0.f};
  for (int ks=0; ks<16; ks++){
    short8 af0 = *(const short8*)(hid + ma*HS + ks*32 + quad*8);
    short8 af1 = *(const short8*)(hid + (16+ma)*HS + ks*32 + quad*8);
    #pragma unroll
    for (int tile=0; tile<2; tile++){
      int cc0 = wave*32 + tile*16;
      short8 bf = *(const short8*)(w2b + (size_t)(cc0 + ma)*512 + ks*32 + quad*8);
      acc2[tile][0] = __builtin_amdgcn_mfma_f32_16x16x32_bf16(af0, bf, acc2[tile][0], 0,0,0);
      acc2[tile][1] = __builtin_amdgcn_mfma_f32_16x16x32_bf16(af1, bf, acc2[tile][1], 0,0,0);
    }
  }
  #pragma unroll
  for (int tile=0; tile<2; tile++){
    int c = wave*32 + tile*16 + ma;
    float bias = b2[c];
    #pragma unroll
    for (int mt=0; mt<2; mt++)
      #pragma unroll
      for (int r=0;r<4;r++){
        int m = mt*16 + quad*4 + r;
        mlpout[(size_t)(pos0+m)*128 + c] = f2b(acc2[tile][mt][r] + bias);
      }
  }
}

// ---------------- kH: final residual add + NHWC->NCHW fp32 out ----------------
__global__ __launch_bounds__(256) void kH_final(const ushort_t* __restrict__ x2,
    const ushort_t* __restrict__ mlpout, float* __restrict__ out){
  __shared__ float tile[64*130];
  int t = threadIdx.x;
  int pos0 = blockIdx.x*64;
  int n = pos0>>14, hw0 = pos0&16383;
  for (int i=0;i<32;i++){
    int e = i*256+t;
    int p = e>>7, c = e&127;
    tile[p*130+c] = b2f(x2[(size_t)pos0*128+e]) + b2f(mlpout[(size_t)pos0*128+e]);
  }
  __syncthreads();
  float* ob = out + (size_t)n*128*HWsz + hw0;
  for (int i=0;i<32;i++){
    int e = i*256+t;
    int c = e>>6, p = e&63;
    ob[(size_t)c*HWsz + p] = tile[p*130+c];
  }
}

extern "C" void kernel_launch(void* const* d_in, const int* in_sizes, int n_in,
                              void* d_out, int out_size, void* d_ws, size_t ws_size,
                              hipStream_t stream){
  const float* x     = (const float*)d_in[0];
  const float* n1w   = (const float*)d_in[1];
  const float* n1b   = (const float*)d_in[2];
  const float* dww   = (const float*)d_in[3];
  const float* dwb   = (const float*)d_in[4];
  const float* dwlnw = (const float*)d_in[5];
  const float* dwlnb = (const float*)d_in[6];
  const float* offw  = (const float*)d_in[7];
  const float* offb  = (const float*)d_in[8];
  const float* maskw = (const float*)d_in[9];
  const float* maskb = (const float*)d_in[10];
  const float* pw    = (const float*)d_in[11];
  const float* pb    = (const float*)d_in[12];
  const float* n2w   = (const float*)d_in[13];
  const float* n2b   = (const float*)d_in[14];
  const float* w1    = (const float*)d_in[15];
  const float* b1    = (const float*)d_in[16];
  const float* w2    = (const float*)d_in[17];
  const float* b2    = (const float*)d_in[18];

  // ws layout:
  //  R0 = ws[ 0,16MB): xcl (kA->kB) -> dcnout (kCD->kE) -> mlpout (kFG->kH)
  //  R1 = ws[16,32MB): x1  (kB->kCD) -> x2 (kE->kFG,kH)
  //  +32MB: w1b(128K), w2b(128K), owmb(32K) bf16; dwwT(4.5K) fp32
  char* wsb = (char*)d_ws;
  ushort_t* R0   = (ushort_t*)(wsb);
  ushort_t* R1   = (ushort_t*)(wsb + (16u<<20));
  ushort_t* w1b  = (ushort_t*)(wsb + (32u<<20));
  ushort_t* w2b  = (ushort_t*)(wsb + (32u<<20) + (128u<<10));
  ushort_t* owmb = (ushort_t*)(wsb + (32u<<20) + (256u<<10));
  float*    dwwT = (float*)(wsb + (32u<<20) + (288u<<10));
  float* out = (float*)d_out;

  hipLaunchKernelGGL(kW_cvt,  dim3(256),   dim3(256), 0, stream, w1, w2, offw, maskw, dww, w1b, w2b, owmb, dwwT);
  hipLaunchKernelGGL(kA_ln1,  dim3(1024),  dim3(256), 0, stream, x, n1w, n1b, R0);
  hipLaunchKernelGGL(kB_dw,   dim3(4096),  dim3(256), 0, stream, R0, dwwT, dwb, dwlnw, dwlnb, R1);
  hipLaunchKernelGGL(kCD_dcn, dim3(4096),  dim3(256), 0, stream, R1, owmb, offb, maskb, R0);
  hipLaunchKernelGGL(kE_outproj, dim3(4096), dim3(256), 0, stream, R0, pw, pb, x, R1);
  hipLaunchKernelGGL(kFG_mfma, dim3(2048), dim3(256), 0, stream, R1, n2w, n2b, w1b, b1, w2b, b2, R0);
  hipLaunchKernelGGL(kH_final, dim3(1024), dim3(256), 0, stream, R1, R0, out);
}

// Round 9
// 316.441 us; speedup vs baseline: 3.9620x; 1.1274x over previous
//
#include <hip/hip_runtime.h>

typedef unsigned short ushort_t;
typedef short short8 __attribute__((ext_vector_type(8)));
typedef float f32x4 __attribute__((ext_vector_type(4)));
typedef ushort_t ushort8v __attribute__((ext_vector_type(8)));

#define HWsz 16384
#define NHWsz 65536
// padded LDS row strides (ushorts): stride%128B != 0 -> 2-way max (free)
#define YS 136
#define HS 520

__device__ __forceinline__ float b2f(ushort_t u){ return __uint_as_float(((unsigned)u)<<16); }
__device__ __forceinline__ ushort_t f2b(float f){
  unsigned x = __float_as_uint(f);
  x += 0x7fffu + ((x>>16)&1u);
  return (ushort_t)(x>>16);
}
__device__ __forceinline__ float gelu_exact(float x){
  return 0.5f*x*(1.0f+erff(x*0.70710678118654752f));
}

// ---------------- kW: weight preprocessing (once per launch) ----------------
__global__ __launch_bounds__(256) void kW_cvt(const float* __restrict__ w1, const float* __restrict__ w2,
    const float* __restrict__ offw, const float* __restrict__ maskw, const float* __restrict__ dww,
    const float* __restrict__ pw,
    ushort_t* __restrict__ w1b, ushort_t* __restrict__ w2b, ushort_t* __restrict__ owmb,
    float* __restrict__ dwwT, ushort_t* __restrict__ pwh, ushort_t* __restrict__ pwl){
  int i = blockIdx.x*256 + threadIdx.x;   // 65536
  w1b[i] = f2b(w1[i]);
  w2b[i] = f2b(w2[i]);
  if (i < 16384){
    int row = i >> 7, k = i & 127;
    float v = 0.f;
    if (row < 72) v = offw[row*128 + k];
    else if (row < 108) v = maskw[(row-72)*128 + k];
    owmb[i] = f2b(v);
    // outproj weights: bf16 hi+lo split (hi+lo ~= fp32 fidelity in MFMA)
    float pv = pw[i];
    ushort_t hi = f2b(pv);
    pwh[i] = hi;
    pwl[i] = f2b(pv - b2f(hi));
  }
  if (i < 1152){
    int k = i >> 7, c = i & 127;
    dwwT[i] = dww[c*9 + k];
  }
}

// ---------------- kA: LN1, NCHW fp32 -> NHWC bf16 ----------------
__global__ __launch_bounds__(256) void kA_ln1(const float* __restrict__ x,
    const float* __restrict__ w, const float* __restrict__ b,
    ushort_t* __restrict__ xcl){
  __shared__ float tile[128*66];
  __shared__ float psum[256], psq[256];
  __shared__ float ms[64], rs[64];
  int t = threadIdx.x;
  int pos0 = blockIdx.x * 64;
  int n = pos0 >> 14, hw0 = pos0 & 16383;
  const float* xb = x + (size_t)n*128*HWsz + hw0;
  for (int i=0;i<32;i++){
    int e = i*256+t;
    int c = e>>6, p = e&63;
    tile[c*66+p] = xb[(size_t)c*HWsz + p];
  }
  __syncthreads();
  {
    int part = t>>6, p = t&63;
    float s=0.f, q=0.f;
    for (int c=part*32; c<part*32+32; c++){ float v = tile[c*66+p]; s+=v; q+=v*v; }
    psum[part*64+p]=s; psq[part*64+p]=q;
  }
  __syncthreads();
  if (t<64){
    float s=psum[t]+psum[64+t]+psum[128+t]+psum[192+t];
    float q=psq[t]+psq[64+t]+psq[128+t]+psq[192+t];
    float m = s*(1.0f/128.0f);
    float v = q*(1.0f/128.0f)-m*m;
    ms[t]=m; rs[t]=rsqrtf(v+1e-6f);
  }
  __syncthreads();
  for (int i=0;i<32;i++){
    int e = i*256+t;
    int p = e>>7, c = e&127;
    float v = (tile[c*66+p]-ms[p])*rs[p]*w[c]+b[c];
    xcl[(size_t)(pos0+p)*128 + c] = f2b(v);
  }
}

// ---------------- kB: depthwise 3x3 + bias + LN + GELU ----------------
__global__ __launch_bounds__(256) void kB_dw(const ushort_t* __restrict__ xcl,
    const float* __restrict__ dwwT, const float* __restrict__ dwb,
    const float* __restrict__ lnw, const float* __restrict__ lnb,
    ushort_t* __restrict__ x1){
  __shared__ float partS[16*17], partQ[16*17];
  __shared__ float ms[16], rs[16];
  int t = threadIdx.x;
  int pos0 = blockIdx.x*16;
  int n = pos0>>14, hw0 = pos0&16383, h = hw0>>7, w0 = hw0&127;
  int pp = t>>4, l = t&15, ch0 = l*8;
  int w = w0 + pp;
  float acc[8];
  {
    float4 b0 = *(const float4*)(dwb + ch0);
    float4 b1 = *(const float4*)(dwb + ch0 + 4);
    acc[0]=b0.x; acc[1]=b0.y; acc[2]=b0.z; acc[3]=b0.w;
    acc[4]=b1.x; acc[5]=b1.y; acc[6]=b1.z; acc[7]=b1.w;
  }
  #pragma unroll
  for (int kh=0; kh<3; kh++){
    int hy = h + kh - 1;
    if ((unsigned)hy < 128u){
      #pragma unroll
      for (int kw=0; kw<3; kw++){
        int wx = w + kw - 1;
        if ((unsigned)wx < 128u){
          ushort8v xv = *(const ushort8v*)(xcl + ((size_t)(n*16384 + hy*128 + wx))*128 + ch0);
          const float* wr = dwwT + (kh*3+kw)*128 + ch0;
          float4 w0v = *(const float4*)(wr);
          float4 w1v = *(const float4*)(wr+4);
          acc[0] += b2f(xv[0])*w0v.x; acc[1] += b2f(xv[1])*w0v.y;
          acc[2] += b2f(xv[2])*w0v.z; acc[3] += b2f(xv[3])*w0v.w;
          acc[4] += b2f(xv[4])*w1v.x; acc[5] += b2f(xv[5])*w1v.y;
          acc[6] += b2f(xv[6])*w1v.z; acc[7] += b2f(xv[7])*w1v.w;
        }
      }
    }
  }
  {
    float s=0.f, q=0.f;
    #pragma unroll
    for (int j=0;j<8;j++){ s+=acc[j]; q+=acc[j]*acc[j]; }
    partS[pp*17+l]=s; partQ[pp*17+l]=q;
  }
  __syncthreads();
  if (t<16){
    float s=0.f, q=0.f;
    for (int i=0;i<16;i++){ s += partS[t*17+i]; q += partQ[t*17+i]; }
    float m = s*(1.0f/128.0f);
    float var = q*(1.0f/128.0f) - m*m;
    ms[t]=m; rs[t]=rsqrtf(var+1e-6f);
  }
  __syncthreads();
  {
    float m = ms[pp], r = rs[pp];
    float4 lw0 = *(const float4*)(lnw + ch0);
    float4 lw1 = *(const float4*)(lnw + ch0 + 4);
    float4 lb0 = *(const float4*)(lnb + ch0);
    float4 lb1 = *(const float4*)(lnb + ch0 + 4);
    float lw[8] = {lw0.x,lw0.y,lw0.z,lw0.w,lw1.x,lw1.y,lw1.z,lw1.w};
    float lb[8] = {lb0.x,lb0.y,lb0.z,lb0.w,lb1.x,lb1.y,lb1.z,lb1.w};
    ushort8v o;
    #pragma unroll
    for (int j=0;j<8;j++){
      float v = (acc[j]-m)*r*lw[j]+lb[j];
      o[j] = f2b(gelu_exact(v));
    }
    *(ushort8v*)(x1 + (size_t)(pos0+pp)*128 + ch0) = o;
  }
}

// ---------------- kCD: MFMA offset/mask + softmax + descriptor + vectorized sampling ----
#define RS 120
__global__ __launch_bounds__(256) void kCD_dcn(const ushort_t* __restrict__ x1,
    const ushort_t* __restrict__ owmb, const float* __restrict__ offb,
    const float* __restrict__ mb, ushort_t* __restrict__ dcnout){
  __shared__ __align__(16) ushort_t xLb[16*YS];
  __shared__ float raw[16*RS];
  __shared__ __align__(16) float descW[576*4];
  __shared__ __align__(16) int   descO[576*4];
  int t = threadIdx.x;
  int pos0 = blockIdx.x*16;
  int n = pos0>>14, hw0 = pos0&16383, h = hw0>>7, w0 = hw0&127;
  const size_t imgbase = (size_t)n*16384*128;

  *(ushort8v*)(xLb + (t>>4)*YS + (t&15)*8) = *(const ushort8v*)(x1 + (size_t)pos0*128 + t*8);
  __syncthreads();

  {
    int wave = t>>6, lane = t&63;
    int ma = lane&15, quad = lane>>4;
    short8 afrag[4];
    #pragma unroll
    for (int ks=0; ks<4; ks++)
      afrag[ks] = *(const short8*)(xLb + ma*YS + ks*32 + quad*8);
    f32x4 acc[2];
    acc[0] = (f32x4){0.f,0.f,0.f,0.f};
    acc[1] = (f32x4){0.f,0.f,0.f,0.f};
    #pragma unroll
    for (int tile=0; tile<2; tile++){
      const ushort_t* brow = owmb + (size_t)(wave*32 + tile*16 + ma)*128 + quad*8;
      #pragma unroll
      for (int ks=0; ks<4; ks++){
        short8 bfrag = *(const short8*)(brow + ks*32);
        acc[tile] = __builtin_amdgcn_mfma_f32_16x16x32_bf16(afrag[ks], bfrag, acc[tile], 0,0,0);
      }
    }
    #pragma unroll
    for (int tile=0; tile<2; tile++){
      int row = wave*32 + tile*16 + ma;
      if (row < 112){
        float bias = (row < 72) ? offb[row] : ((row < 108) ? mb[row-72] : 0.f);
        #pragma unroll
        for (int r=0;r<4;r++){
          int m = quad*4 + r;
          raw[m*RS + row] = acc[tile][r] + bias;
        }
      }
    }
  }
  __syncthreads();

  if (t < 64){
    int p = t>>2, g = t&3;
    float* mr = raw + p*RS + 72 + g*9;
    float mx = -1e30f;
    for (int q=0;q<9;q++) mx = fmaxf(mx, mr[q]);
    float e[9]; float ssum=0.f;
    for (int q=0;q<9;q++){ e[q]=expf(mr[q]-mx); ssum+=e[q]; }
    float inv = 1.0f/ssum;
    for (int q=0;q<9;q++) mr[q] = e[q]*inv;
  }
  __syncthreads();

  for (int it=0; it<3; it++){
    int tid = t + 256*it;
    if (tid < 576){
      int pp = tid/36, rem = tid - pp*36;
      int g = rem/9, p = rem - g*9;
      int i = p/3, j = p - i*3;
      float ox = raw[pp*RS + 2*(g*9+p)];
      float oy = raw[pp*RS + 2*(g*9+p)+1];
      float mval = raw[pp*RS + 72 + g*9 + p];
      float px = (float)(w0 + pp + i - 1) + ox;
      float py = (float)(h + j - 1) + oy;
      float fx0 = floorf(px), fy0 = floorf(py);
      int ix0 = (int)fx0, iy0 = (int)fy0;
      float fx = px - fx0, fy = py - fy0;
      float vx0 = ((unsigned)ix0     < 128u) ? 1.f : 0.f;
      float vx1 = ((unsigned)(ix0+1) < 128u) ? 1.f : 0.f;
      float vy0 = ((unsigned)iy0     < 128u) ? 1.f : 0.f;
      float vy1 = ((unsigned)(iy0+1) < 128u) ? 1.f : 0.f;
      int cx0 = min(max(ix0,0),127), cx1 = min(max(ix0+1,0),127);
      int cy0 = min(max(iy0,0),127), cy1 = min(max(iy0+1,0),127);
      float4 wv;
      wv.x = (1.f-fx)*(1.f-fy)*mval*vx0*vy0;
      wv.y = fx*(1.f-fy)*mval*vx1*vy0;
      wv.z = (1.f-fx)*fy*mval*vx0*vy1;
      wv.w = fx*fy*mval*vx1*vy1;
      int4 ov;
      ov.x = (cy0*128+cx0)*128;
      ov.y = (cy0*128+cx1)*128;
      ov.z = (cy1*128+cx0)*128;
      ov.w = (cy1*128+cx1)*128;
      *(float4*)(descW + tid*4) = wv;
      *(int4*)(descO + tid*4) = ov;
    }
  }
  __syncthreads();

  {
    int pp = t>>4, l = t&15;
    int ch0 = l*8, g = l>>2;
    const ushort_t* ib = x1 + imgbase + ch0;
    float acc[8];
    #pragma unroll
    for (int j=0;j<8;j++) acc[j]=0.f;
    int dbase = pp*36 + g*9;
    #pragma unroll
    for (int p=0;p<9;p++){
      float4 wv = *(const float4*)(descW + (dbase+p)*4);
      int4  ov = *(const int4*)(descO + (dbase+p)*4);
      ushort8v v00 = *(const ushort8v*)(ib + ov.x);
      ushort8v v10 = *(const ushort8v*)(ib + ov.y);
      ushort8v v01 = *(const ushort8v*)(ib + ov.z);
      ushort8v v11 = *(const ushort8v*)(ib + ov.w);
      #pragma unroll
      for (int j=0;j<8;j++){
        float s = wv.x*b2f(v00[j]) + wv.y*b2f(v10[j]) + wv.z*b2f(v01[j]) + wv.w*b2f(v11[j]);
        acc[j] += s;
      }
    }
    ushort8v outv;
    #pragma unroll
    for (int j=0;j<8;j++) outv[j] = f2b(acc[j]);
    *(ushort8v*)(dcnout + (size_t)(pos0+pp)*128 + ch0) = outv;
  }
}

// ---------------- kE v2: MFMA outproj (hi+lo weights) + residual -> x2 bf16 ----------------
// 32 positions/block, 4 waves, no LDS, no barriers.
__global__ __launch_bounds__(256) void kE_outproj(const ushort_t* __restrict__ dcnout,
    const ushort_t* __restrict__ pwh, const ushort_t* __restrict__ pwl,
    const float* __restrict__ pb, const float* __restrict__ x, ushort_t* __restrict__ x2){
  int t = threadIdx.x;
  int pos0 = blockIdx.x*32;
  int n = pos0>>14, hw0 = pos0&16383;
  int wave = t>>6, lane = t&63;
  int ma = lane&15, quad = lane>>4;

  short8 af[2][4];
  #pragma unroll
  for (int mt=0; mt<2; mt++)
    #pragma unroll
    for (int ks=0; ks<4; ks++)
      af[mt][ks] = *(const short8*)(dcnout + (size_t)(pos0+mt*16+ma)*128 + ks*32 + quad*8);

  f32x4 acc[2][2];
  #pragma unroll
  for (int i=0;i<2;i++){ acc[i][0]=(f32x4){0.f,0.f,0.f,0.f}; acc[i][1]=(f32x4){0.f,0.f,0.f,0.f}; }
  #pragma unroll
  for (int tile=0; tile<2; tile++){
    int c0 = wave*32 + tile*16;
    const ushort_t* bh = pwh + (size_t)(c0 + ma)*128 + quad*8;
    const ushort_t* bl = pwl + (size_t)(c0 + ma)*128 + quad*8;
    #pragma unroll
    for (int ks=0; ks<4; ks++){
      short8 bfh = *(const short8*)(bh + ks*32);
      short8 bfl = *(const short8*)(bl + ks*32);
      #pragma unroll
      for (int mt=0; mt<2; mt++){
        acc[tile][mt] = __builtin_amdgcn_mfma_f32_16x16x32_bf16(af[mt][ks], bfh, acc[tile][mt], 0,0,0);
        acc[tile][mt] = __builtin_amdgcn_mfma_f32_16x16x32_bf16(af[mt][ks], bfl, acc[tile][mt], 0,0,0);
      }
    }
  }
  #pragma unroll
  for (int tile=0; tile<2; tile++){
    int c = wave*32 + tile*16 + ma;
    float bias = pb[c];
    const float* xb = x + ((size_t)(n*128) + c)*HWsz + hw0;
    #pragma unroll
    for (int mt=0; mt<2; mt++){
      f32x4 xr = *(const f32x4*)(xb + mt*16 + quad*4);
      #pragma unroll
      for (int r=0;r<4;r++){
        int m = mt*16 + quad*4 + r;
        x2[(size_t)(pos0+m)*128 + c] = f2b(acc[tile][mt][r] + bias + xr[r]);
      }
    }
  }
}

// ---------------- kS: LN2 stats (mean, rstd) per position ----------------
// same partial grouping as round-8 kFG (8 lanes x 16 ch) -> identical rounding.
__global__ __launch_bounds__(256) void kS_stats(const ushort_t* __restrict__ x2,
    float* __restrict__ stats){
  __shared__ float partS[32*9], partQ[32*9];
  int t = threadIdx.x;
  int pos0 = blockIdx.x*32;
  int tg = t>>3, li = t&7, c0 = li*16;
  {
    ushort8v xv0 = *(const ushort8v*)(x2 + (size_t)(pos0+tg)*128 + c0);
    ushort8v xv1 = *(const ushort8v*)(x2 + (size_t)(pos0+tg)*128 + c0 + 8);
    float s=0.f, q=0.f;
    #pragma unroll
    for (int j=0;j<8;j++){ float v=b2f(xv0[j]); s+=v; q+=v*v; }
    #pragma unroll
    for (int j=0;j<8;j++){ float v=b2f(xv1[j]); s+=v; q+=v*v; }
    partS[tg*9+li]=s; partQ[tg*9+li]=q;
  }
  __syncthreads();
  if (t < 32){
    float s=0.f, q=0.f;
    for (int i=0;i<8;i++){ s += partS[t*9+i]; q += partQ[t*9+i]; }
    float m = s*(1.0f/128.0f);
    float var = q*(1.0f/128.0f) - m*m;
    float2 st; st.x = m; st.y = rsqrtf(var+1e-6f);
    *(float2*)(stats + 2*(pos0+t)) = st;
  }
}

// ---------------- kFG v4: MFMA MLP w/ fused LN2-apply + residual + NCHW store ----------------
// 32 positions/block; A from global (normalized on the fly); LDS = hid only; ONE barrier.
__global__ __launch_bounds__(256) void kFG_mfma(const ushort_t* __restrict__ x2,
    const float* __restrict__ stats,
    const float* __restrict__ n2w, const float* __restrict__ n2b,
    const ushort_t* __restrict__ w1b, const float* __restrict__ b1,
    const ushort_t* __restrict__ w2b, const float* __restrict__ b2,
    float* __restrict__ out){
  __shared__ __align__(16) ushort_t hid[32*HS];
  int t = threadIdx.x;
  int pos0 = blockIdx.x*32;
  int n = pos0>>14, hw0 = pos0&16383;
  int wave = t>>6, lane = t&63;
  int ma = lane&15, quad = lane>>4;

  // --- build FC1 A-fragments from global + stats (no LDS, no barrier) ---
  float2 st[2];
  st[0] = *(const float2*)(stats + 2*(pos0 + ma));
  st[1] = *(const float2*)(stats + 2*(pos0 + 16 + ma));
  short8 af[2][4];
  #pragma unroll
  for (int ks=0; ks<4; ks++){
    int cb = ks*32 + quad*8;
    f32x4 nw0 = *(const f32x4*)(n2w + cb);
    f32x4 nw1 = *(const f32x4*)(n2w + cb + 4);
    f32x4 nb0 = *(const f32x4*)(n2b + cb);
    f32x4 nb1 = *(const f32x4*)(n2b + cb + 4);
    #pragma unroll
    for (int mt=0; mt<2; mt++){
      ushort8v xv = *(const ushort8v*)(x2 + (size_t)(pos0+mt*16+ma)*128 + cb);
      float m = st[mt].x, r = st[mt].y;
      short8 a;
      #pragma unroll
      for (int j=0;j<4;j++) a[j]   = (short)f2b((b2f(xv[j])  -m)*r*nw0[j] + nb0[j]);
      #pragma unroll
      for (int j=0;j<4;j++) a[4+j] = (short)f2b((b2f(xv[4+j])-m)*r*nw1[j] + nb1[j]);
      af[mt][ks] = a;
    }
  }

  // --- FC1: wave covers n in [wave*128, wave*128+128) ---
  f32x4 acc[8][2];
  #pragma unroll
  for (int i=0;i<8;i++){ acc[i][0]=(f32x4){0.f,0.f,0.f,0.f}; acc[i][1]=(f32x4){0.f,0.f,0.f,0.f}; }
  int nbase = wave*128;
  #pragma unroll
  for (int tile=0; tile<8; tile++){
    const ushort_t* brow = w1b + (size_t)(nbase + tile*16 + ma)*128 + quad*8;
    short8 bf[4];
    #pragma unroll
    for (int ks=0; ks<4; ks++) bf[ks] = *(const short8*)(brow + ks*32);
    #pragma unroll
    for (int mt=0; mt<2; mt++)
      #pragma unroll
      for (int ks=0; ks<4; ks++)
        acc[tile][mt] = __builtin_amdgcn_mfma_f32_16x16x32_bf16(af[mt][ks], bf[ks], acc[tile][mt], 0,0,0);
  }
  #pragma unroll
  for (int tile=0; tile<8; tile++){
    int nn = nbase + tile*16 + ma;
    float bias = b1[nn];
    #pragma unroll
    for (int mt=0; mt<2; mt++)
      #pragma unroll
      for (int r=0;r<4;r++){
        int m = mt*16 + quad*4 + r;
        hid[m*HS + nn] = f2b(gelu_exact(acc[tile][mt][r] + bias));
      }
  }
  __syncthreads();

  // --- FC2: wave covers c in [wave*32, wave*32+32); K=512 ---
  f32x4 acc2[2][2];
  acc2[0][0]=(f32x4){0.f,0.f,0.f,0.f}; acc2[0][1]=(f32x4){0.f,0.f,0.f,0.f};
  acc2[1][0]=(f32x4){0.f,0.f,0.f,0.f}; acc2[1][1]=(f32x4){0.f,0.f,0.f,0.f};
  for (int ks=0; ks<16; ks++){
    short8 af0 = *(const short8*)(hid + ma*HS + ks*32 + quad*8);
    short8 af1 = *(const short8*)(hid + (16+ma)*HS + ks*32 + quad*8);
    #pragma unroll
    for (int tile=0; tile<2; tile++){
      int cc0 = wave*32 + tile*16;
      short8 bf = *(const short8*)(w2b + (size_t)(cc0 + ma)*512 + ks*32 + quad*8);
      acc2[tile][0] = __builtin_amdgcn_mfma_f32_16x16x32_bf16(af0, bf, acc2[tile][0], 0,0,0);
      acc2[tile][1] = __builtin_amdgcn_mfma_f32_16x16x32_bf16(af1, bf, acc2[tile][1], 0,0,0);
    }
  }
  // --- epilogue: + bias + residual x2, NCHW fp32 store (fused kH) ---
  #pragma unroll
  for (int tile=0; tile<2; tile++){
    int c = wave*32 + tile*16 + ma;
    float bias = b2[c];
    float* ob = out + ((size_t)(n*128) + c)*HWsz + hw0;
    #pragma unroll
    for (int mt=0; mt<2; mt++){
      f32x4 o;
      #pragma unroll
      for (int r=0;r<4;r++){
        int m = mt*16 + quad*4 + r;
        float res = b2f(x2[(size_t)(pos0+m)*128 + c]);
        o[r] = acc2[tile][mt][r] + bias + res;
      }
      *(f32x4*)(ob + mt*16 + quad*4) = o;
    }
  }
}

extern "C" void kernel_launch(void* const* d_in, const int* in_sizes, int n_in,
                              void* d_out, int out_size, void* d_ws, size_t ws_size,
                              hipStream_t stream){
  const float* x     = (const float*)d_in[0];
  const float* n1w   = (const float*)d_in[1];
  const float* n1b   = (const float*)d_in[2];
  const float* dww   = (const float*)d_in[3];
  const float* dwb   = (const float*)d_in[4];
  const float* dwlnw = (const float*)d_in[5];
  const float* dwlnb = (const float*)d_in[6];
  const float* offw  = (const float*)d_in[7];
  const float* offb  = (const float*)d_in[8];
  const float* maskw = (const float*)d_in[9];
  const float* maskb = (const float*)d_in[10];
  const float* pw    = (const float*)d_in[11];
  const float* pb    = (const float*)d_in[12];
  const float* n2w   = (const float*)d_in[13];
  const float* n2b   = (const float*)d_in[14];
  const float* w1    = (const float*)d_in[15];
  const float* b1    = (const float*)d_in[16];
  const float* w2    = (const float*)d_in[17];
  const float* b2    = (const float*)d_in[18];

  // ws layout:
  //  R0 = ws[ 0,16MB): xcl (kA->kB) -> dcnout (kCD->kE)
  //  R1 = ws[16,32MB): x1  (kB->kCD) -> x2 (kE->kS,kFG)
  //  +32MB: w1b(128K) w2b(128K) owmb(32K) pwh(32K) pwl(32K) bf16; dwwT(8K) fp32; stats(512K) fp32
  char* wsb = (char*)d_ws;
  ushort_t* R0   = (ushort_t*)(wsb);
  ushort_t* R1   = (ushort_t*)(wsb + (16u<<20));
  ushort_t* w1b  = (ushort_t*)(wsb + (32u<<20));
  ushort_t* w2b  = (ushort_t*)(wsb + (32u<<20) + (128u<<10));
  ushort_t* owmb = (ushort_t*)(wsb + (32u<<20) + (256u<<10));
  ushort_t* pwh  = (ushort_t*)(wsb + (32u<<20) + (288u<<10));
  ushort_t* pwl  = (ushort_t*)(wsb + (32u<<20) + (320u<<10));
  float*    dwwT = (float*)(wsb + (32u<<20) + (352u<<10));
  float*    stats= (float*)(wsb + (32u<<20) + (360u<<10));
  float* out = (float*)d_out;

  hipLaunchKernelGGL(kW_cvt,  dim3(256),   dim3(256), 0, stream, w1, w2, offw, maskw, dww, pw, w1b, w2b, owmb, dwwT, pwh, pwl);
  hipLaunchKernelGGL(kA_ln1,  dim3(1024),  dim3(256), 0, stream, x, n1w, n1b, R0);
  hipLaunchKernelGGL(kB_dw,   dim3(4096),  dim3(256), 0, stream, R0, dwwT, dwb, dwlnw, dwlnb, R1);
  hipLaunchKernelGGL(kCD_dcn, dim3(4096),  dim3(256), 0, stream, R1, owmb, offb, maskb, R0);
  hipLaunchKernelGGL(kE_outproj, dim3(2048), dim3(256), 0, stream, R0, pwh, pwl, pb, x, R1);
  hipLaunchKernelGGL(kS_stats, dim3(2048), dim3(256), 0, stream, R1, stats);
  hipLaunchKernelGGL(kFG_mfma, dim3(2048), dim3(256), 0, stream, R1, stats, n2w, n2b, w1b, b1, w2b, b2, out);
}

// Round 10
// 316.346 us; speedup vs baseline: 3.9632x; 1.0003x over previous
//
#include <hip/hip_runtime.h>

typedef unsigned short ushort_t;
typedef short short8 __attribute__((ext_vector_type(8)));
typedef float f32x4 __attribute__((ext_vector_type(4)));
typedef ushort_t ushort8v __attribute__((ext_vector_type(8)));
typedef ushort_t ushort4v __attribute__((ext_vector_type(4)));

#define HWsz 16384
#define NHWsz 65536
// padded LDS row strides (ushorts): stride%128B != 0 -> 2-way max (free)
#define YS 136
#define HS 520

__device__ __forceinline__ float b2f(ushort_t u){ return __uint_as_float(((unsigned)u)<<16); }
__device__ __forceinline__ ushort_t f2b(float f){
  unsigned x = __float_as_uint(f);
  x += 0x7fffu + ((x>>16)&1u);
  return (ushort_t)(x>>16);
}
__device__ __forceinline__ float gelu_exact(float x){
  return 0.5f*x*(1.0f+erff(x*0.70710678118654752f));
}

// ---------------- kW: weight preprocessing (once per launch) ----------------
__global__ __launch_bounds__(256) void kW_cvt(const float* __restrict__ w1, const float* __restrict__ w2,
    const float* __restrict__ offw, const float* __restrict__ maskw, const float* __restrict__ dww,
    const float* __restrict__ pw, const float* __restrict__ offb, const float* __restrict__ mb,
    ushort_t* __restrict__ w1b, ushort_t* __restrict__ w2b, ushort_t* __restrict__ owmb,
    float* __restrict__ dwwT, ushort_t* __restrict__ pwh, ushort_t* __restrict__ pwl,
    float* __restrict__ obm){
  int i = blockIdx.x*256 + threadIdx.x;   // 65536
  w1b[i] = f2b(w1[i]);
  w2b[i] = f2b(w2[i]);
  if (i < 16384){
    int row = i >> 7, k = i & 127;
    float v = 0.f;
    if (row < 72) v = offw[row*128 + k];
    else if (row < 108) v = maskw[(row-72)*128 + k];
    owmb[i] = f2b(v);
    float pv = pw[i];
    ushort_t hi = f2b(pv);
    pwh[i] = hi;
    pwl[i] = f2b(pv - b2f(hi));
  }
  if (i < 1152){
    int k = i >> 7, c = i & 127;
    dwwT[i] = dww[c*9 + k];
  }
  if (i < 128){
    obm[i] = (i < 72) ? offb[i] : ((i < 108) ? mb[i-72] : 0.f);
  }
}

// ---------------- kA: LN1, NCHW fp32 -> NHWC bf16 ----------------
__global__ __launch_bounds__(256) void kA_ln1(const float* __restrict__ x,
    const float* __restrict__ w, const float* __restrict__ b,
    ushort_t* __restrict__ xcl){
  __shared__ float tile[128*66];
  __shared__ float psum[256], psq[256];
  __shared__ float ms[64], rs[64];
  int t = threadIdx.x;
  int pos0 = blockIdx.x * 64;
  int n = pos0 >> 14, hw0 = pos0 & 16383;
  const float* xb = x + (size_t)n*128*HWsz + hw0;
  for (int i=0;i<32;i++){
    int e = i*256+t;
    int c = e>>6, p = e&63;
    tile[c*66+p] = xb[(size_t)c*HWsz + p];
  }
  __syncthreads();
  {
    int part = t>>6, p = t&63;
    float s=0.f, q=0.f;
    for (int c=part*32; c<part*32+32; c++){ float v = tile[c*66+p]; s+=v; q+=v*v; }
    psum[part*64+p]=s; psq[part*64+p]=q;
  }
  __syncthreads();
  if (t<64){
    float s=psum[t]+psum[64+t]+psum[128+t]+psum[192+t];
    float q=psq[t]+psq[64+t]+psq[128+t]+psq[192+t];
    float m = s*(1.0f/128.0f);
    float v = q*(1.0f/128.0f)-m*m;
    ms[t]=m; rs[t]=rsqrtf(v+1e-6f);
  }
  __syncthreads();
  for (int i=0;i<32;i++){
    int e = i*256+t;
    int p = e>>7, c = e&127;
    float v = (tile[c*66+p]-ms[p])*rs[p]*w[c]+b[c];
    xcl[(size_t)(pos0+p)*128 + c] = f2b(v);
  }
}

// ---------------- kB: depthwise 3x3 + bias + LN + GELU ----------------
__global__ __launch_bounds__(256) void kB_dw(const ushort_t* __restrict__ xcl,
    const float* __restrict__ dwwT, const float* __restrict__ dwb,
    const float* __restrict__ lnw, const float* __restrict__ lnb,
    ushort_t* __restrict__ x1){
  __shared__ float partS[16*17], partQ[16*17];
  __shared__ float ms[16], rs[16];
  int t = threadIdx.x;
  int pos0 = blockIdx.x*16;
  int n = pos0>>14, hw0 = pos0&16383, h = hw0>>7, w0 = hw0&127;
  int pp = t>>4, l = t&15, ch0 = l*8;
  int w = w0 + pp;
  float acc[8];
  {
    float4 b0 = *(const float4*)(dwb + ch0);
    float4 b1 = *(const float4*)(dwb + ch0 + 4);
    acc[0]=b0.x; acc[1]=b0.y; acc[2]=b0.z; acc[3]=b0.w;
    acc[4]=b1.x; acc[5]=b1.y; acc[6]=b1.z; acc[7]=b1.w;
  }
  #pragma unroll
  for (int kh=0; kh<3; kh++){
    int hy = h + kh - 1;
    if ((unsigned)hy < 128u){
      #pragma unroll
      for (int kw=0; kw<3; kw++){
        int wx = w + kw - 1;
        if ((unsigned)wx < 128u){
          ushort8v xv = *(const ushort8v*)(xcl + ((size_t)(n*16384 + hy*128 + wx))*128 + ch0);
          const float* wr = dwwT + (kh*3+kw)*128 + ch0;
          float4 w0v = *(const float4*)(wr);
          float4 w1v = *(const float4*)(wr+4);
          acc[0] += b2f(xv[0])*w0v.x; acc[1] += b2f(xv[1])*w0v.y;
          acc[2] += b2f(xv[2])*w0v.z; acc[3] += b2f(xv[3])*w0v.w;
          acc[4] += b2f(xv[4])*w1v.x; acc[5] += b2f(xv[5])*w1v.y;
          acc[6] += b2f(xv[6])*w1v.z; acc[7] += b2f(xv[7])*w1v.w;
        }
      }
    }
  }
  {
    float s=0.f, q=0.f;
    #pragma unroll
    for (int j=0;j<8;j++){ s+=acc[j]; q+=acc[j]*acc[j]; }
    partS[pp*17+l]=s; partQ[pp*17+l]=q;
  }
  __syncthreads();
  if (t<16){
    float s=0.f, q=0.f;
    for (int i=0;i<16;i++){ s += partS[t*17+i]; q += partQ[t*17+i]; }
    float m = s*(1.0f/128.0f);
    float var = q*(1.0f/128.0f) - m*m;
    ms[t]=m; rs[t]=rsqrtf(var+1e-6f);
  }
  __syncthreads();
  {
    float m = ms[pp], r = rs[pp];
    float4 lw0 = *(const float4*)(lnw + ch0);
    float4 lw1 = *(const float4*)(lnw + ch0 + 4);
    float4 lb0 = *(const float4*)(lnb + ch0);
    float4 lb1 = *(const float4*)(lnb + ch0 + 4);
    float lw[8] = {lw0.x,lw0.y,lw0.z,lw0.w,lw1.x,lw1.y,lw1.z,lw1.w};
    float lb[8] = {lb0.x,lb0.y,lb0.z,lb0.w,lb1.x,lb1.y,lb1.z,lb1.w};
    ushort8v o;
    #pragma unroll
    for (int j=0;j<8;j++){
      float v = (acc[j]-m)*r*lw[j]+lb[j];
      o[j] = f2b(gelu_exact(v));
    }
    *(ushort8v*)(x1 + (size_t)(pos0+pp)*128 + ch0) = o;
  }
}

// ---------------- kCD: MFMA offset/mask + softmax + descriptor + vectorized sampling ----
#define RS 120
__global__ __launch_bounds__(256) void kCD_dcn(const ushort_t* __restrict__ x1,
    const ushort_t* __restrict__ owmb, const float* __restrict__ obm,
    ushort_t* __restrict__ dcnout){
  __shared__ __align__(16) ushort_t xLb[16*YS];
  __shared__ float raw[16*RS];
  __shared__ __align__(16) float descW[576*4];
  __shared__ __align__(16) int   descO[576*4];
  int t = threadIdx.x;
  int pos0 = blockIdx.x*16;
  int n = pos0>>14, hw0 = pos0&16383, h = hw0>>7, w0 = hw0&127;
  const size_t imgbase = (size_t)n*16384*128;

  *(ushort8v*)(xLb + (t>>4)*YS + (t&15)*8) = *(const ushort8v*)(x1 + (size_t)pos0*128 + t*8);
  __syncthreads();

  // phase 2: MFMA linear, operand-swapped: D-row = weight-row, D-col = position
  {
    int wave = t>>6, lane = t&63;
    int ma = lane&15, quad = lane>>4;
    short8 afrag[4];
    #pragma unroll
    for (int ks=0; ks<4; ks++)
      afrag[ks] = *(const short8*)(xLb + ma*YS + ks*32 + quad*8);
    f32x4 acc[2];
    acc[0] = (f32x4){0.f,0.f,0.f,0.f};
    acc[1] = (f32x4){0.f,0.f,0.f,0.f};
    #pragma unroll
    for (int tile=0; tile<2; tile++){
      const ushort_t* brow = owmb + (size_t)(wave*32 + tile*16 + ma)*128 + quad*8;
      #pragma unroll
      for (int ks=0; ks<4; ks++){
        short8 bfrag = *(const short8*)(brow + ks*32);
        acc[tile] = __builtin_amdgcn_mfma_f32_16x16x32_bf16(bfrag, afrag[ks], acc[tile], 0,0,0);
      }
    }
    #pragma unroll
    for (int tile=0; tile<2; tile++){
      int row0 = wave*32 + tile*16 + quad*4;
      if (row0 < 112){
        f32x4 bias4 = *(const f32x4*)(obm + row0);
        f32x4 o;
        #pragma unroll
        for (int r=0;r<4;r++) o[r] = acc[tile][r] + bias4[r];
        *(f32x4*)(raw + ma*RS + row0) = o;
      }
    }
  }
  __syncthreads();

  if (t < 64){
    int p = t>>2, g = t&3;
    float* mr = raw + p*RS + 72 + g*9;
    float mx = -1e30f;
    for (int q=0;q<9;q++) mx = fmaxf(mx, mr[q]);
    float e[9]; float ssum=0.f;
    for (int q=0;q<9;q++){ e[q]=expf(mr[q]-mx); ssum+=e[q]; }
    float inv = 1.0f/ssum;
    for (int q=0;q<9;q++) mr[q] = e[q]*inv;
  }
  __syncthreads();

  for (int it=0; it<3; it++){
    int tid = t + 256*it;
    if (tid < 576){
      int pp = tid/36, rem = tid - pp*36;
      int g = rem/9, p = rem - g*9;
      int i = p/3, j = p - i*3;
      float ox = raw[pp*RS + 2*(g*9+p)];
      float oy = raw[pp*RS + 2*(g*9+p)+1];
      float mval = raw[pp*RS + 72 + g*9 + p];
      float px = (float)(w0 + pp + i - 1) + ox;
      float py = (float)(h + j - 1) + oy;
      float fx0 = floorf(px), fy0 = floorf(py);
      int ix0 = (int)fx0, iy0 = (int)fy0;
      float fx = px - fx0, fy = py - fy0;
      float vx0 = ((unsigned)ix0     < 128u) ? 1.f : 0.f;
      float vx1 = ((unsigned)(ix0+1) < 128u) ? 1.f : 0.f;
      float vy0 = ((unsigned)iy0     < 128u) ? 1.f : 0.f;
      float vy1 = ((unsigned)(iy0+1) < 128u) ? 1.f : 0.f;
      int cx0 = min(max(ix0,0),127), cx1 = min(max(ix0+1,0),127);
      int cy0 = min(max(iy0,0),127), cy1 = min(max(iy0+1,0),127);
      float4 wv;
      wv.x = (1.f-fx)*(1.f-fy)*mval*vx0*vy0;
      wv.y = fx*(1.f-fy)*mval*vx1*vy0;
      wv.z = (1.f-fx)*fy*mval*vx0*vy1;
      wv.w = fx*fy*mval*vx1*vy1;
      int4 ov;
      ov.x = (cy0*128+cx0)*128;
      ov.y = (cy0*128+cx1)*128;
      ov.z = (cy1*128+cx0)*128;
      ov.w = (cy1*128+cx1)*128;
      *(float4*)(descW + tid*4) = wv;
      *(int4*)(descO + tid*4) = ov;
    }
  }
  __syncthreads();

  {
    int pp = t>>4, l = t&15;
    int ch0 = l*8, g = l>>2;
    const ushort_t* ib = x1 + imgbase + ch0;
    float acc[8];
    #pragma unroll
    for (int j=0;j<8;j++) acc[j]=0.f;
    int dbase = pp*36 + g*9;
    #pragma unroll
    for (int p=0;p<9;p++){
      float4 wv = *(const float4*)(descW + (dbase+p)*4);
      int4  ov = *(const int4*)(descO + (dbase+p)*4);
      ushort8v v00 = *(const ushort8v*)(ib + ov.x);
      ushort8v v10 = *(const ushort8v*)(ib + ov.y);
      ushort8v v01 = *(const ushort8v*)(ib + ov.z);
      ushort8v v11 = *(const ushort8v*)(ib + ov.w);
      #pragma unroll
      for (int j=0;j<8;j++){
        float s = wv.x*b2f(v00[j]) + wv.y*b2f(v10[j]) + wv.z*b2f(v01[j]) + wv.w*b2f(v11[j]);
        acc[j] += s;
      }
    }
    ushort8v outv;
    #pragma unroll
    for (int j=0;j<8;j++) outv[j] = f2b(acc[j]);
    *(ushort8v*)(dcnout + (size_t)(pos0+pp)*128 + ch0) = outv;
  }
}

// ---------------- kE v3: MFMA outproj (hi+lo) + residual + fused LN2 stats ----------------
// operand-swapped: D-row = out-channel, D-col = position. 32 pos/block.
__global__ __launch_bounds__(256) void kE_outproj(const ushort_t* __restrict__ dcnout,
    const ushort_t* __restrict__ pwh, const ushort_t* __restrict__ pwl,
    const float* __restrict__ pb, const float* __restrict__ x, ushort_t* __restrict__ x2,
    float* __restrict__ stats){
  __shared__ float partS[32*17], partQ[32*17];
  int t = threadIdx.x;
  int pos0 = blockIdx.x*32;
  int n = pos0>>14, hw0 = pos0&16383;
  int wave = t>>6, lane = t&63;
  int ma = lane&15, quad = lane>>4;

  short8 af[2][4];
  #pragma unroll
  for (int mt=0; mt<2; mt++)
    #pragma unroll
    for (int ks=0; ks<4; ks++)
      af[mt][ks] = *(const short8*)(dcnout + (size_t)(pos0+mt*16+ma)*128 + ks*32 + quad*8);

  f32x4 acc[2][2];
  #pragma unroll
  for (int i=0;i<2;i++){ acc[i][0]=(f32x4){0.f,0.f,0.f,0.f}; acc[i][1]=(f32x4){0.f,0.f,0.f,0.f}; }
  #pragma unroll
  for (int tile=0; tile<2; tile++){
    int c0 = wave*32 + tile*16;
    const ushort_t* bh = pwh + (size_t)(c0 + ma)*128 + quad*8;
    const ushort_t* bl = pwl + (size_t)(c0 + ma)*128 + quad*8;
    #pragma unroll
    for (int ks=0; ks<4; ks++){
      short8 bfh = *(const short8*)(bh + ks*32);
      short8 bfl = *(const short8*)(bl + ks*32);
      #pragma unroll
      for (int mt=0; mt<2; mt++){
        acc[tile][mt] = __builtin_amdgcn_mfma_f32_16x16x32_bf16(bfh, af[mt][ks], acc[tile][mt], 0,0,0);
        acc[tile][mt] = __builtin_amdgcn_mfma_f32_16x16x32_bf16(bfl, af[mt][ks], acc[tile][mt], 0,0,0);
      }
    }
  }
  // epilogue: D[row=c][col=pos]; per (tile,mt): 4 consecutive channels at one position
  float sAcc[2], qAcc[2];
  sAcc[0]=0.f; sAcc[1]=0.f; qAcc[0]=0.f; qAcc[1]=0.f;
  #pragma unroll
  for (int tile=0; tile<2; tile++){
    int c0 = wave*32 + tile*16 + quad*4;
    f32x4 bias4 = *(const f32x4*)(pb + c0);
    #pragma unroll
    for (int mt=0; mt<2; mt++){
      int p = mt*16 + ma;
      ushort4v ov;
      #pragma unroll
      for (int r=0;r<4;r++){
        float res = x[((size_t)(n*128) + c0 + r)*HWsz + hw0 + p];
        float v = acc[tile][mt][r] + bias4[r] + res;
        ushort_t ub = f2b(v);
        ov[r] = ub;
        float vb = b2f(ub);
        sAcc[mt] += vb; qAcc[mt] += vb*vb;
      }
      *(ushort4v*)(x2 + (size_t)(pos0+p)*128 + c0) = ov;
    }
  }
  #pragma unroll
  for (int mt=0; mt<2; mt++){
    int p = mt*16 + ma;
    partS[p*17 + wave*4 + quad] = sAcc[mt];
    partQ[p*17 + wave*4 + quad] = qAcc[mt];
  }
  __syncthreads();
  if (t < 32){
    float s=0.f, q=0.f;
    for (int i=0;i<16;i++){ s += partS[t*17+i]; q += partQ[t*17+i]; }
    float m = s*(1.0f/128.0f);
    float var = q*(1.0f/128.0f) - m*m;
    float2 st; st.x = m; st.y = rsqrtf(var+1e-6f);
    *(float2*)(stats + 2*(pos0+t)) = st;
  }
}

// ---------------- kFG v5: MFMA MLP, operand-swapped, fused LN2-apply + residual + NCHW store ----
__global__ __launch_bounds__(256) void kFG_mfma(const ushort_t* __restrict__ x2,
    const float* __restrict__ stats,
    const float* __restrict__ n2w, const float* __restrict__ n2b,
    const ushort_t* __restrict__ w1b, const float* __restrict__ b1,
    const ushort_t* __restrict__ w2b, const float* __restrict__ b2,
    float* __restrict__ out){
  __shared__ __align__(16) ushort_t hid[32*HS];
  int t = threadIdx.x;
  int pos0 = blockIdx.x*32;
  int n = pos0>>14, hw0 = pos0&16383;
  int wave = t>>6, lane = t&63;
  int ma = lane&15, quad = lane>>4;

  // build normalized A... (x-fragments; these are the MFMA *second* operand now)
  float2 st[2];
  st[0] = *(const float2*)(stats + 2*(pos0 + ma));
  st[1] = *(const float2*)(stats + 2*(pos0 + 16 + ma));
  short8 af[2][4];
  #pragma unroll
  for (int ks=0; ks<4; ks++){
    int cb = ks*32 + quad*8;
    f32x4 nw0 = *(const f32x4*)(n2w + cb);
    f32x4 nw1 = *(const f32x4*)(n2w + cb + 4);
    f32x4 nb0 = *(const f32x4*)(n2b + cb);
    f32x4 nb1 = *(const f32x4*)(n2b + cb + 4);
    #pragma unroll
    for (int mt=0; mt<2; mt++){
      ushort8v xv = *(const ushort8v*)(x2 + (size_t)(pos0+mt*16+ma)*128 + cb);
      float m = st[mt].x, r = st[mt].y;
      short8 a;
      #pragma unroll
      for (int j=0;j<4;j++) a[j]   = (short)f2b((b2f(xv[j])  -m)*r*nw0[j] + nb0[j]);
      #pragma unroll
      for (int j=0;j<4;j++) a[4+j] = (short)f2b((b2f(xv[4+j])-m)*r*nw1[j] + nb1[j]);
      af[mt][ks] = a;
    }
  }

  // --- FC1: mfma(w1_frag, x_frag) -> D[row=n][col=pos] ---
  f32x4 acc[8][2];
  #pragma unroll
  for (int i=0;i<8;i++){ acc[i][0]=(f32x4){0.f,0.f,0.f,0.f}; acc[i][1]=(f32x4){0.f,0.f,0.f,0.f}; }
  int nbase = wave*128;
  #pragma unroll
  for (int tile=0; tile<8; tile++){
    const ushort_t* brow = w1b + (size_t)(nbase + tile*16 + ma)*128 + quad*8;
    short8 bf[4];
    #pragma unroll
    for (int ks=0; ks<4; ks++) bf[ks] = *(const short8*)(brow + ks*32);
    #pragma unroll
    for (int mt=0; mt<2; mt++)
      #pragma unroll
      for (int ks=0; ks<4; ks++)
        acc[tile][mt] = __builtin_amdgcn_mfma_f32_16x16x32_bf16(bf[ks], af[mt][ks], acc[tile][mt], 0,0,0);
  }
  #pragma unroll
  for (int tile=0; tile<8; tile++){
    int n0 = nbase + tile*16 + quad*4;
    f32x4 bias4 = *(const f32x4*)(b1 + n0);
    #pragma unroll
    for (int mt=0; mt<2; mt++){
      int p = mt*16 + ma;
      ushort4v hv;
      #pragma unroll
      for (int r=0;r<4;r++) hv[r] = f2b(gelu_exact(acc[tile][mt][r] + bias4[r]));
      *(ushort4v*)(hid + p*HS + n0) = hv;
    }
  }
  __syncthreads();

  // --- FC2: mfma(w2_frag, hid_frag) -> D[row=c][col=pos] ---
  f32x4 acc2[2][2];
  acc2[0][0]=(f32x4){0.f,0.f,0.f,0.f}; acc2[0][1]=(f32x4){0.f,0.f,0.f,0.f};
  acc2[1][0]=(f32x4){0.f,0.f,0.f,0.f}; acc2[1][1]=(f32x4){0.f,0.f,0.f,0.f};
  for (int ks=0; ks<16; ks++){
    short8 hf0 = *(const short8*)(hid + ma*HS + ks*32 + quad*8);
    short8 hf1 = *(const short8*)(hid + (16+ma)*HS + ks*32 + quad*8);
    #pragma unroll
    for (int tile=0; tile<2; tile++){
      int cc0 = wave*32 + tile*16;
      short8 bf = *(const short8*)(w2b + (size_t)(cc0 + ma)*512 + ks*32 + quad*8);
      acc2[tile][0] = __builtin_amdgcn_mfma_f32_16x16x32_bf16(bf, hf0, acc2[tile][0], 0,0,0);
      acc2[tile][1] = __builtin_amdgcn_mfma_f32_16x16x32_bf16(bf, hf1, acc2[tile][1], 0,0,0);
    }
  }
  // --- epilogue: + bias + residual (8B bf16 load), NCHW fp32 coalesced store ---
  #pragma unroll
  for (int tile=0; tile<2; tile++){
    int c0 = wave*32 + tile*16 + quad*4;
    f32x4 bias4 = *(const f32x4*)(b2 + c0);
    #pragma unroll
    for (int mt=0; mt<2; mt++){
      int p = mt*16 + ma;
      ushort4v rv = *(const ushort4v*)(x2 + (size_t)(pos0+p)*128 + c0);
      #pragma unroll
      for (int r=0;r<4;r++){
        float v = acc2[tile][mt][r] + bias4[r] + b2f(rv[r]);
        out[((size_t)(n*128) + c0 + r)*HWsz + hw0 + p] = v;
      }
    }
  }
}

extern "C" void kernel_launch(void* const* d_in, const int* in_sizes, int n_in,
                              void* d_out, int out_size, void* d_ws, size_t ws_size,
                              hipStream_t stream){
  const float* x     = (const float*)d_in[0];
  const float* n1w   = (const float*)d_in[1];
  const float* n1b   = (const float*)d_in[2];
  const float* dww   = (const float*)d_in[3];
  const float* dwb   = (const float*)d_in[4];
  const float* dwlnw = (const float*)d_in[5];
  const float* dwlnb = (const float*)d_in[6];
  const float* offw  = (const float*)d_in[7];
  const float* offb  = (const float*)d_in[8];
  const float* maskw = (const float*)d_in[9];
  const float* maskb = (const float*)d_in[10];
  const float* pw    = (const float*)d_in[11];
  const float* pb    = (const float*)d_in[12];
  const float* n2w   = (const float*)d_in[13];
  const float* n2b   = (const float*)d_in[14];
  const float* w1    = (const float*)d_in[15];
  const float* b1    = (const float*)d_in[16];
  const float* w2    = (const float*)d_in[17];
  const float* b2    = (const float*)d_in[18];

  // ws layout:
  //  R0 = ws[ 0,16MB): xcl (kA->kB) -> dcnout (kCD->kE)
  //  R1 = ws[16,32MB): x1  (kB->kCD) -> x2 (kE->kFG)
  //  +32MB: w1b(128K) w2b(128K) owmb(32K) pwh(32K) pwl(32K) bf16; dwwT+obm fp32; stats(512K) fp32
  char* wsb = (char*)d_ws;
  ushort_t* R0   = (ushort_t*)(wsb);
  ushort_t* R1   = (ushort_t*)(wsb + (16u<<20));
  ushort_t* w1b  = (ushort_t*)(wsb + (32u<<20));
  ushort_t* w2b  = (ushort_t*)(wsb + (32u<<20) + (128u<<10));
  ushort_t* owmb = (ushort_t*)(wsb + (32u<<20) + (256u<<10));
  ushort_t* pwh  = (ushort_t*)(wsb + (32u<<20) + (288u<<10));
  ushort_t* pwl  = (ushort_t*)(wsb + (32u<<20) + (320u<<10));
  float*    dwwT = (float*)(wsb + (32u<<20) + (352u<<10));
  float*    obm  = (float*)(wsb + (32u<<20) + (358u<<10));
  float*    stats= (float*)(wsb + (32u<<20) + (360u<<10));
  float* out = (float*)d_out;

  hipLaunchKernelGGL(kW_cvt,  dim3(256),   dim3(256), 0, stream, w1, w2, offw, maskw, dww, pw, offb, maskb, w1b, w2b, owmb, dwwT, pwh, pwl, obm);
  hipLaunchKernelGGL(kA_ln1,  dim3(1024),  dim3(256), 0, stream, x, n1w, n1b, R0);
  hipLaunchKernelGGL(kB_dw,   dim3(4096),  dim3(256), 0, stream, R0, dwwT, dwb, dwlnw, dwlnb, R1);
  hipLaunchKernelGGL(kCD_dcn, dim3(4096),  dim3(256), 0, stream, R1, owmb, obm, R0);
  hipLaunchKernelGGL(kE_outproj, dim3(2048), dim3(256), 0, stream, R0, pwh, pwl, pb, x, R1, stats);
  hipLaunchKernelGGL(kFG_mfma, dim3(2048), dim3(256), 0, stream, R1, stats, n2w, n2b, w1b, b1, w2b, b2, out);
}